// Round 12
// baseline (1523.206 us; speedup 1.0000x reference)
//
#include <hip/hip_runtime.h>
#include <cstdint>
#include <cstddef>

#define SEQ   128
#define BB    32
#define EE    1024
#define HH    1024
#define G4    4096
#define VV    32000
#define NROWS 4096   // SEQ*BB

typedef _Float16 h16x8 __attribute__((ext_vector_type(8)));
typedef _Float16 h16x4 __attribute__((ext_vector_type(4)));
typedef float f32x4  __attribute__((ext_vector_type(4)));

#define AS_G(p) ((const __attribute__((address_space(1))) void*)(p))
#define AS_L(p) ((__attribute__((address_space(3))) void*)(p))

__device__ __forceinline__ float sigmf(float x) { return 1.0f / (1.0f + expf(-x)); }

// ---------------- ws layout (bytes) ----------------
// hfrag = monotonic slot ring: slot s holds [3 layers][32768 f16] (196608 B).
// slots 0..2: dedicated region; slots 3..129 overlay EMB+WIH0+TARGET (dead
// during the recurrence).
#define OFF_SYNC    0ull                      // pad[64] + arrive[256] strided 128B
#define OFF_HFRAG0  40960ull                  // 3 slots  * 196608 = 589824
#define OFF_EMB     630784ull                 // [4096][1024] f16   (8388608)
#define OFF_WIH0    9019392ull                // [4096][1024] f16   (8388608)
#define OFF_TARGET  17408000ull               // [4096][1024] f16   (8388608)
#define OFF_HT      25796608ull               // [4096][1024] f16   (8388608)
#define OFF_HFRAGH  630784ull                 // 127 slots * 196608 (overlay)
#define OFF_X0      34185216ull               // [4096][4096] f16   (33554432)
#define OFF_WP4     67739648ull               // 256 wg * 65536 f16 (33554432)
#define OFF_WP0     101294080ull              // 256 wg * 16384 f16 (8388608)
#define OFF_EMBW    109682688ull              // [32000][1024] f16  (65536000)
#define OFF_WIN     175218688ull              // [1024][1024] f16   (2097152)
#define OFF_WOUT    177315840ull              // [1024][2048] f16   (4194304)
#define OFF_ENC     181510144ull              // [64][32][1024] f16 (4194304)
#define OFF_H2ALL   185704448ull              // [4096][1024] f16   (8388608)
#define OFF_CONCAT  194093056ull              // [4096][2048] f16   (16777216)
#define WS_NEEDED   210870272ull

// ---------------- f32 -> f16 convert (vectorized, grid-stride) ----------------
__global__ __launch_bounds__(256) void k_conv(const float* __restrict__ s,
                                              _Float16* __restrict__ d, int n4) {
  int i = blockIdx.x * blockDim.x + threadIdx.x;
  int st = gridDim.x * blockDim.x;
  for (; i < n4; i += st) {
    float4 v = ((const float4*)s)[i];
    h16x4 o; o[0] = (_Float16)v.x; o[1] = (_Float16)v.y; o[2] = (_Float16)v.z; o[3] = (_Float16)v.w;
    ((h16x4*)d)[i] = o;
  }
}

// ---------------- embedding gather -> f16 ----------------
__global__ __launch_bounds__(256) void k_gather(const int* __restrict__ tok,
                                                const float* __restrict__ embW,
                                                _Float16* __restrict__ emb) {
  int row = blockIdx.x;                 // row = t*32+b
  int t = tok[row];
  float4 v = ((const float4*)(embW + (size_t)t * EE))[threadIdx.x];
  h16x4 o; o[0] = (_Float16)v.x; o[1] = (_Float16)v.y; o[2] = (_Float16)v.z; o[3] = (_Float16)v.w;
  ((h16x4*)(emb + (size_t)row * EE))[threadIdx.x] = o;
}

// ---------------- pack 4 LDS-resident matrices (Wih1,Whh1,Wih2,Whh2) ----------------
// wg w owns hidden units 4*wp..4*wp+3 with wp=(w&7)*32+(w>>3)  (XCD-local X0 lines)
__global__ __launch_bounds__(256) void k_packw4(const float* __restrict__ Wih,
                                                const float* __restrict__ Whh,
                                                _Float16* __restrict__ out) {
  int i = blockIdx.x * blockDim.x + threadIdx.x;
  int st = gridDim.x * blockDim.x;
  const int total = 256 * 65536;
  for (; i < total; i += st) {
    int w = i >> 16, rem = i & 65535;
    int wp = (w & 7) * 32 + (w >> 3);
    int mat = rem >> 14, jj = (rem >> 10) & 15, k = rem & 1023;
    int layer = 1 + (mat >> 1), isHH = mat & 1;
    int row = ((jj >> 2) << 10) + (wp << 2) + (jj & 3);
    int ks = k ^ ((jj & 7) << 3);
    const float* src = (isHH ? Whh : Wih) + (size_t)layer * G4 * 1024 + (size_t)row * 1024 + ks;
    out[i] = (_Float16)(*src);
  }
}

// ---------------- pack Whh0 fragment-linear: [w][ks 0..31][lane 0..63][e 0..7] ----------------
__global__ __launch_bounds__(256) void k_packw0(const float* __restrict__ Whh,
                                                _Float16* __restrict__ out) {
  int i = blockIdx.x * blockDim.x + threadIdx.x;
  int st = gridDim.x * blockDim.x;
  const int total = 256 * 16384;
  for (; i < total; i += st) {
    int w = i >> 14, rem = i & 16383;
    int wp = (w & 7) * 32 + (w >> 3);
    int ks = rem >> 9, lane = (rem >> 3) & 63, e = rem & 7;
    int jj = lane & 15, q = lane >> 4;
    int row = ((jj >> 2) << 10) + (wp << 2) + (jj & 3);
    int k = ks * 32 + q * 8 + e;
    out[i] = (_Float16)Whh[(size_t)row * 1024 + k];   // layer 0
  }
}

// ---------------- init: sync flags + initial h into slots 0..2 ----------------
__global__ __launch_bounds__(256) void k_init(const float* __restrict__ h0,
                                              _Float16* __restrict__ hfrag0,
                                              unsigned* __restrict__ sync) {
  int i = blockIdx.x * blockDim.x + threadIdx.x;
  if (i < 64 + 8192) sync[i] = 0u;   // pad + arrive (strided)
  if (i >= 3 * BB * HH) return;
  int l = i >> 15, rem = i & 32767;
  int b = rem >> 10, n = rem & 1023;
  int tbb = b >> 4, ks = n >> 5, q = (n >> 3) & 3, e = n & 7;
  int lane2 = (b & 15) | (q << 4);
  hfrag0[(size_t)l * 131072 + ((size_t)(tbb * 32 + ks) * 64 + lane2) * 8 + e] =
      (_Float16)h0[i];
}

// ---------------- generic 128x128 BT GEMM (A[M,K] f16, B[N,K] f16) ----------------
// EPI: 1 = f16 ; 2 = f16(tanh)   (big GEMMs use k_gemm256)
template <int EPI>
__global__ __launch_bounds__(256) void k_gemm(const _Float16* __restrict__ A,
                                              const _Float16* __restrict__ B,
                                              void* __restrict__ C, int M, int N, int K,
                                              const float* __restrict__ bias1,
                                              const float* __restrict__ bias2) {
  __shared__ _Float16 As[2][128 * 32];
  __shared__ _Float16 Bs[2][128 * 32];
  const int ntn = N / 128;
  const int nwg = gridDim.x;
  const int bid = (blockIdx.x & 7) * (nwg >> 3) + (blockIdx.x >> 3);
  const int tm = bid / ntn, tn = bid % ntn;
  const int tid = threadIdx.x, lane = tid & 63;
  const int wv = tid >> 6, wr = wv >> 1, wc = wv & 1;
  f32x4 acc[4][4] = {};

  auto stage = [&](int buf, int k0) {
#pragma unroll
    for (int i = 0; i < 2; ++i) {
      int eo = (i * 256 + tid) * 8;
      int r = eo >> 5, c = eo & 31;
      __builtin_amdgcn_global_load_lds(AS_G(A + (size_t)(tm * 128 + r) * K + k0 + c),
                                       AS_L(&As[buf][eo]), 16, 0, 0);
      __builtin_amdgcn_global_load_lds(AS_G(B + (size_t)(tn * 128 + r) * K + k0 + c),
                                       AS_L(&Bs[buf][eo]), 16, 0, 0);
    }
  };
  stage(0, 0);
  __syncthreads();
  const int nk = K / 32;
  for (int kt = 0; kt < nk; ++kt) {
    if (kt + 1 < nk) stage((kt + 1) & 1, (kt + 1) * 32);
    const int buf = kt & 1;
    h16x8 af[4], bfr[4];
#pragma unroll
    for (int mi = 0; mi < 4; ++mi)
      af[mi] = *(const h16x8*)&As[buf][(wr * 64 + mi * 16 + (lane & 15)) * 32 + (lane >> 4) * 8];
#pragma unroll
    for (int ni = 0; ni < 4; ++ni)
      bfr[ni] = *(const h16x8*)&Bs[buf][(wc * 64 + ni * 16 + (lane & 15)) * 32 + (lane >> 4) * 8];
#pragma unroll
    for (int mi = 0; mi < 4; ++mi)
#pragma unroll
      for (int ni = 0; ni < 4; ++ni)
        acc[mi][ni] = __builtin_amdgcn_mfma_f32_16x16x32_f16(af[mi], bfr[ni], acc[mi][ni], 0, 0, 0);
    __syncthreads();
  }
  const int rbase = tm * 128 + wr * 64;
  const int cbase = tn * 128 + wc * 64;
#pragma unroll
  for (int mi = 0; mi < 4; ++mi) {
#pragma unroll
    for (int ni = 0; ni < 4; ++ni) {
#pragma unroll
      for (int r = 0; r < 4; ++r) {
        int mm = rbase + mi * 16 + (lane >> 4) * 4 + r;
        int nn = cbase + ni * 16 + (lane & 15);
        float v = acc[mi][ni][r];
        if (EPI == 1) {
          ((_Float16*)C)[(size_t)mm * N + nn] = (_Float16)v;
        } else {
          ((_Float16*)C)[(size_t)mm * N + nn] = (_Float16)tanhf(v);
        }
      }
    }
  }
}

// ---------------- 256x256 BT GEMM v2: 1024 thr, 16 waves (4x4), 2-slot ring ----------------
// Wave tile 64x64 -> acc 4x4 (64 VGPR) -> 4 waves/SIMD resident (VGPR<=128).
// Counted vmcnt(2): tile t+1's 2 loads/thread stay in flight across the barrier.
// EPI: 0 = f32 + bias1 ; 1 = f16 + bias1 + bias2
template <int EPI>
__global__ __launch_bounds__(1024, 4) void k_gemm256(const _Float16* __restrict__ A,
                                                     const _Float16* __restrict__ B,
                                                     void* __restrict__ C, int M, int N, int K,
                                                     const float* __restrict__ bias1,
                                                     const float* __restrict__ bias2) {
  extern __shared__ char glds[];
  _Float16* Asl = (_Float16*)glds;                     // [2][256*32]
  _Float16* Bsl = (_Float16*)(glds + 2 * 8192 * 2);    // [2][256*32]
  const int ntn = N / 256;
  const int nwg = gridDim.x;
  const int bid = (blockIdx.x & 7) * (nwg >> 3) + (blockIdx.x >> 3);
  const int tm = bid / ntn, tn = bid % ntn;
  const int tid = threadIdx.x, lane = tid & 63;
  const int wid = tid >> 6, wm = wid >> 2, wn = wid & 3;   // 4x4 waves
  const int fr = lane & 15, fc = lane >> 4;
  const int srow = tid >> 2, sg = tid & 3;   // staging: 1 granule per matrix per thread

  f32x4 acc[4][4] = {};
  const int nt = K / 32;

  auto stage = [&](int t) {
    const int slot = t & 1;
    const size_t kof = (size_t)t * 32 + sg * 8;
    __builtin_amdgcn_global_load_lds(AS_G(A + (size_t)(tm * 256 + srow) * K + kof),
                                     AS_L(&Asl[slot * 8192 + srow * 32 + sg * 8]), 16, 0, 0);
    __builtin_amdgcn_global_load_lds(AS_G(B + (size_t)(tn * 256 + srow) * K + kof),
                                     AS_L(&Bsl[slot * 8192 + srow * 32 + sg * 8]), 16, 0, 0);
  };

  stage(0);
  for (int t = 0; t < nt; ++t) {
    if (t + 1 < nt) {
      stage(t + 1);
      asm volatile("s_waitcnt vmcnt(2)" ::: "memory");   // tile t landed; t+1 in flight
    } else {
      asm volatile("s_waitcnt vmcnt(0)" ::: "memory");   // tail drain
    }
    asm volatile("s_barrier" ::: "memory");              // tile t visible to all waves
    const int slot = t & 1;
    const _Float16* as = &Asl[slot * 8192];
    const _Float16* bs = &Bsl[slot * 8192];
    h16x8 af[4], bf[4];
#pragma unroll
    for (int mi = 0; mi < 4; ++mi)
      af[mi] = *(const h16x8*)&as[(wm * 64 + mi * 16 + fr) * 32 + fc * 8];
#pragma unroll
    for (int ni = 0; ni < 4; ++ni)
      bf[ni] = *(const h16x8*)&bs[(wn * 64 + ni * 16 + fr) * 32 + fc * 8];
    __builtin_amdgcn_s_setprio(1);
#pragma unroll
    for (int mi = 0; mi < 4; ++mi)
#pragma unroll
      for (int ni = 0; ni < 4; ++ni)
        acc[mi][ni] = __builtin_amdgcn_mfma_f32_16x16x32_f16(af[mi], bf[ni], acc[mi][ni], 0, 0, 0);
    __builtin_amdgcn_s_setprio(0);
    asm volatile("s_barrier" ::: "memory");   // reads of slot done before it is restaged
  }

  const int rbase = tm * 256 + wm * 64;
  const int cbase = tn * 256 + wn * 64;
#pragma unroll
  for (int mi = 0; mi < 4; ++mi) {
#pragma unroll
    for (int ni = 0; ni < 4; ++ni) {
#pragma unroll
      for (int r = 0; r < 4; ++r) {
        int mm = rbase + mi * 16 + fc * 4 + r;
        int nn = cbase + ni * 16 + fr;
        float v = acc[mi][ni][r];
        if (EPI == 0) {
          ((float*)C)[(size_t)mm * N + nn] = v + bias1[nn];
        } else {
          ((_Float16*)C)[(size_t)mm * N + nn] = (_Float16)(v + bias1[nn] + bias2[nn]);
        }
      }
    }
  }
}

// ---------------- persistent pipelined LSTM recurrence (unchanged from R11) ----------------
__global__ __launch_bounds__(512) void k_recur(const _Float16* __restrict__ Wp4,
                                               const _Float16* __restrict__ Wp0,
                                               const _Float16* __restrict__ X0bf,
                                               _Float16* __restrict__ hfrag0,
                                               _Float16* __restrict__ hfragH,
                                               _Float16* __restrict__ h2all,
                                               _Float16* __restrict__ concat,
                                               const float* __restrict__ bih,
                                               const float* __restrict__ bhh,
                                               const float* __restrict__ c0p,
                                               unsigned* __restrict__ sync) {
  extern __shared__ char lds[];
  _Float16* ldsW = (_Float16*)lds;                 // 65536 f16
  float* redbuf = (float*)(lds + 131072);          // [3][3][2][256]
  _Float16* hstage = (_Float16*)(lds + 131072);    // [3][128] (reused after redbuf)
  float* gbuf = (float*)(lds + 149504);            // [3][32][16]
  unsigned* arrive = sync + 64;                    // strided: arrive[w*32]

  const int w = blockIdx.x;
  const int wp = (w & 7) * 32 + (w >> 3);          // XCD-local unit-block remap
  const int tid = threadIdx.x, lane = tid & 63, wv = tid >> 6;
  const int tb = wv & 1, kq = wv >> 1;
  const int row = (lane >> 4) * 4, col = lane & 15;

  for (int i = 0; i < 16; ++i) {
    int eo = (i * 512 + tid) * 8;
    *(h16x8*)&ldsW[eo] = *(const h16x8*)(Wp4 + (size_t)w * 65536 + eo);
  }
  h16x8 w0reg[8];
#pragma unroll
  for (int i = 0; i < 8; ++i)
    w0reg[i] = *(const h16x8*)(Wp0 + (size_t)w * 16384 + ((size_t)(kq * 8 + i) * 64 + lane) * 8);

  const int eb = tid >> 2, eni = tid & 3, en = wp * 4 + eni;
  float c0r = 0.f, c1r = 0.f, c2r = 0.f;
  float b1r[4] = {0, 0, 0, 0}, b2r[4] = {0, 0, 0, 0};
  if (tid < 128) {
    c0r = c0p[0 * BB * HH + eb * HH + en];
    c1r = c0p[1 * BB * HH + eb * HH + en];
    c2r = c0p[2 * BB * HH + eb * HH + en];
#pragma unroll
    for (int g = 0; g < 4; ++g) {
      b1r[g] = bih[1 * G4 + g * 1024 + en] + bhh[1 * G4 + g * 1024 + en];
      b2r[g] = bih[2 * G4 + g * 1024 + en] + bhh[2 * G4 + g * 1024 + en];
    }
  }
  const int pk_l = tid >> 5, pk_r = tid & 31;
  const size_t pk_idx = ((size_t)(((pk_r >> 4) * 32 + (wp >> 3)) * 64 + (pk_r & 15) +
                                  (((wp >> 1) & 3) << 4))) * 8 + 4 * (wp & 1);
  __syncthreads();

  for (int tau = 0; tau < 130; ++tau) {
    const _Float16* rb = (tau < 3) ? (hfrag0 + (size_t)tau * 98304)
                                   : (hfragH + (size_t)(tau - 3) * 98304);
    _Float16* wb = (tau + 1 < 3) ? (hfrag0 + (size_t)(tau + 1) * 98304)
                                 : (hfragH + (size_t)(tau - 2) * 98304);
    const _Float16* h0r = rb;
    const _Float16* h1r = rb + 32768;
    const _Float16* h2r = rb + 65536;

    h16x8 a0[8], a1[8], a2[8];
#pragma unroll
    for (int i = 0; i < 8; ++i) {
      int ks = kq * 8 + i;
      size_t off = ((size_t)(tb * 32 + ks) * 64 + lane) * 8;
      a0[i] = *(const h16x8*)(h0r + off);
      a1[i] = *(const h16x8*)(h1r + off);
      a2[i] = *(const h16x8*)(h2r + off);
    }
    float xg0 = 0.f, xg1 = 0.f, xg2 = 0.f, xg3 = 0.f;
    if (tid < 128 && tau < 128) {
      size_t xb = ((size_t)(tau * BB + eb)) * G4 + en;
      xg0 = (float)X0bf[xb];        xg1 = (float)X0bf[xb + 1024];
      xg2 = (float)X0bf[xb + 2048]; xg3 = (float)X0bf[xb + 3072];
    }
    f32x4 acc0 = {}, acc1 = {}, acc2 = {};
#pragma unroll
    for (int i = 0; i < 8; ++i) {
      int ks = kq * 8 + i;
      int jj = lane & 15, q = lane >> 4;
      int kk = (ks * 32 + q * 8) ^ ((jj & 7) << 3);
      const h16x8 bw1i = *(const h16x8*)&ldsW[0 * 16384 + jj * 1024 + kk];
      const h16x8 bw1h = *(const h16x8*)&ldsW[1 * 16384 + jj * 1024 + kk];
      const h16x8 bw2i = *(const h16x8*)&ldsW[2 * 16384 + jj * 1024 + kk];
      const h16x8 bw2h = *(const h16x8*)&ldsW[3 * 16384 + jj * 1024 + kk];
      acc0 = __builtin_amdgcn_mfma_f32_16x16x32_f16(a0[i], w0reg[i], acc0, 0, 0, 0);
      acc1 = __builtin_amdgcn_mfma_f32_16x16x32_f16(a0[i], bw1i, acc1, 0, 0, 0);
      acc1 = __builtin_amdgcn_mfma_f32_16x16x32_f16(a1[i], bw1h, acc1, 0, 0, 0);
      acc2 = __builtin_amdgcn_mfma_f32_16x16x32_f16(a1[i], bw2i, acc2, 0, 0, 0);
      acc2 = __builtin_amdgcn_mfma_f32_16x16x32_f16(a2[i], bw2h, acc2, 0, 0, 0);
    }
    if (kq >= 1) {
      int s = kq - 1;
#pragma unroll
      for (int r = 0; r < 4; ++r) {
        redbuf[((0 * 3 + s) * 2 + tb) * 256 + (row + r) * 16 + col] = acc0[r];
        redbuf[((1 * 3 + s) * 2 + tb) * 256 + (row + r) * 16 + col] = acc1[r];
        redbuf[((2 * 3 + s) * 2 + tb) * 256 + (row + r) * 16 + col] = acc2[r];
      }
    }
    __syncthreads();
    if (kq == 0) {
#pragma unroll
      for (int r = 0; r < 4; ++r) {
        float v0 = acc0[r], v1 = acc1[r], v2 = acc2[r];
#pragma unroll
        for (int s = 0; s < 3; ++s) {
          v0 += redbuf[((0 * 3 + s) * 2 + tb) * 256 + (row + r) * 16 + col];
          v1 += redbuf[((1 * 3 + s) * 2 + tb) * 256 + (row + r) * 16 + col];
          v2 += redbuf[((2 * 3 + s) * 2 + tb) * 256 + (row + r) * 16 + col];
        }
        gbuf[(0 * 32 + tb * 16 + row + r) * 16 + col] = v0;
        gbuf[(1 * 32 + tb * 16 + row + r) * 16 + col] = v1;
        gbuf[(2 * 32 + tb * 16 + row + r) * 16 + col] = v2;
      }
    }
    __syncthreads();
    if (tid < 128) {
      if (tau < 128) {
        float gi = gbuf[(0 * 32 + eb) * 16 + eni] + xg0;
        float gf = gbuf[(0 * 32 + eb) * 16 + 4 + eni] + xg1;
        float gg = gbuf[(0 * 32 + eb) * 16 + 8 + eni] + xg2;
        float go = gbuf[(0 * 32 + eb) * 16 + 12 + eni] + xg3;
        c0r = sigmf(gf) * c0r + sigmf(gi) * tanhf(gg);
        hstage[0 * 128 + tid] = (_Float16)(sigmf(go) * tanhf(c0r));
      }
      if (tau >= 1 && tau < 129) {
        float gi = gbuf[(1 * 32 + eb) * 16 + eni] + b1r[0];
        float gf = gbuf[(1 * 32 + eb) * 16 + 4 + eni] + b1r[1];
        float gg = gbuf[(1 * 32 + eb) * 16 + 8 + eni] + b1r[2];
        float go = gbuf[(1 * 32 + eb) * 16 + 12 + eni] + b1r[3];
        c1r = sigmf(gf) * c1r + sigmf(gi) * tanhf(gg);
        hstage[1 * 128 + tid] = (_Float16)(sigmf(go) * tanhf(c1r));
      }
      if (tau >= 2) {
        float gi = gbuf[(2 * 32 + eb) * 16 + eni] + b2r[0];
        float gf = gbuf[(2 * 32 + eb) * 16 + 4 + eni] + b2r[1];
        float gg = gbuf[(2 * 32 + eb) * 16 + 8 + eni] + b2r[2];
        float go = gbuf[(2 * 32 + eb) * 16 + 12 + eni] + b2r[3];
        c2r = sigmf(gf) * c2r + sigmf(gi) * tanhf(gg);
        float h = sigmf(go) * tanhf(c2r);
        _Float16 hb = (_Float16)h;
        hstage[2 * 128 + tid] = hb;
        int t2 = tau - 2;
        h2all[(size_t)(t2 * BB + eb) * HH + en] = hb;
        concat[(size_t)(t2 * BB + eb) * 2048 + 1024 + en] = hb;
      }
    }
    __syncthreads();
    {
      bool act = (tid < 96) &&
                 ((pk_l == 0) ? (tau < 128)
                  : (pk_l == 1) ? (tau >= 1 && tau < 129)
                                : (tau >= 2 && tau < 129));
      if (act) {
        unsigned long long v = *(const unsigned long long*)&hstage[pk_l * 128 + pk_r * 4];
        __hip_atomic_store(
            (unsigned long long*)(wb + (size_t)pk_l * 32768 + pk_idx), v,
            __ATOMIC_RELAXED, __HIP_MEMORY_SCOPE_AGENT);
      }
      asm volatile("s_waitcnt vmcnt(0)" ::: "memory");
    }
    __syncthreads();
    if (tid == 0)
      __hip_atomic_store(&arrive[w * 32], (unsigned)(tau + 1), __ATOMIC_RELAXED,
                         __HIP_MEMORY_SCOPE_AGENT);
    if (tau < 129) {
      if (tid < 64) {
        for (;;) {
          bool ok = true;
#pragma unroll
          for (int j = 0; j < 4; ++j) {
            unsigned v = __hip_atomic_load(&arrive[(tid * 4 + j) * 32], __ATOMIC_RELAXED,
                                           __HIP_MEMORY_SCOPE_AGENT);
            ok &= (v >= (unsigned)(tau + 1));
          }
          if (__all(ok)) break;
          __builtin_amdgcn_s_sleep(1);
        }
        asm volatile("" ::: "memory");
      }
      __syncthreads();
    }
  }
}

// ---------------- attention v2: enc[.,b,.] staged ONCE in LDS, 16 t per block ----------------
// grid = 32 b x 8 t-chunks = 256 blocks; enc LDS traffic 16MB total (was ~1GB).
__global__ __launch_bounds__(256) void k_attn(const _Float16* __restrict__ target,
                                              const _Float16* __restrict__ encb,
                                              _Float16* __restrict__ concat) {
  extern __shared__ _Float16 elds[];   // [64][1024] f16 = 128KB
  __shared__ float sc[64];
  __shared__ float att[64];
  const int b = blockIdx.x >> 3, tc = blockIdx.x & 7;
  const int tid = threadIdx.x, lane = tid & 63, wv = tid >> 6;

  // stage enc[.,b,.]: 8192 x 16B granules, LDS-linear (legal for global_load_lds)
  for (int it = 0; it < 32; ++it) {
    int g = it * 256 + tid;
    __builtin_amdgcn_global_load_lds(
        AS_G(encb + ((size_t)((g >> 7) * 32 + b)) * 1024 + (g & 127) * 8),
        AS_L(elds + (size_t)g * 8), 16, 0, 0);
  }
  asm volatile("s_waitcnt vmcnt(0)" ::: "memory");
  __syncthreads();

  for (int ti = 0; ti < 16; ++ti) {
    const int m = (tc * 16 + ti) * 32 + b;
    const h16x8* tp = (const h16x8*)(target + (size_t)m * EE + lane * 16);
    h16x8 tg0 = tp[0], tg1 = tp[1];
#pragma unroll 4
    for (int si = 0; si < 16; ++si) {
      int s = wv * 16 + si;
      const h16x8* ep = (const h16x8*)(elds + (size_t)s * EE + lane * 16);
      h16x8 e0 = ep[0], e1 = ep[1];
      float a = 0.f;
#pragma unroll
      for (int j = 0; j < 8; ++j) a += (float)e0[j] * (float)tg0[j];
#pragma unroll
      for (int j = 0; j < 8; ++j) a += (float)e1[j] * (float)tg1[j];
#pragma unroll
      for (int off = 32; off >= 1; off >>= 1) a += __shfl_xor(a, off);
      if (lane == 0) sc[s] = a;
    }
    __syncthreads();
    if (wv == 0) {
      float v = sc[lane], mx = v;
#pragma unroll
      for (int off = 32; off >= 1; off >>= 1) mx = fmaxf(mx, __shfl_xor(mx, off));
      float e = expf(v - mx), sm = e;
#pragma unroll
      for (int off = 32; off >= 1; off >>= 1) sm += __shfl_xor(sm, off);
      att[lane] = e / sm;
    }
    __syncthreads();
    int e4 = tid * 4;
    float a0 = 0, a1 = 0, a2 = 0, a3 = 0;
    for (int s = 0; s < 64; ++s) {
      float wgt = att[s];
      h16x4 ev = *(const h16x4*)(elds + (size_t)s * EE + e4);
      a0 += wgt * (float)ev[0]; a1 += wgt * (float)ev[1];
      a2 += wgt * (float)ev[2]; a3 += wgt * (float)ev[3];
    }
    h16x4 o; o[0] = (_Float16)a0; o[1] = (_Float16)a1; o[2] = (_Float16)a2; o[3] = (_Float16)a3;
    *(h16x4*)(concat + (size_t)m * 2048 + e4) = o;
    __syncthreads();   // protect sc/att before next ti
  }
}

// ---------------- host ----------------
extern "C" void kernel_launch(void* const* d_in, const int* in_sizes, int n_in,
                              void* d_out, int out_size, void* d_ws, size_t ws_size,
                              hipStream_t stream) {
  const int* tokens = (const int*)d_in[0];
  const float* embW = (const float*)d_in[1];
  const float* Wih = (const float*)d_in[2];
  const float* Whh = (const float*)d_in[3];
  const float* bih = (const float*)d_in[4];
  const float* bhh = (const float*)d_in[5];
  const float* Win = (const float*)d_in[6];
  const float* Wout = (const float*)d_in[7];
  const float* finalb = (const float*)d_in[8];
  const float* enc = (const float*)d_in[9];
  const float* h0 = (const float*)d_in[10];
  const float* c0 = (const float*)d_in[11];
  (void)in_sizes; (void)n_in; (void)out_size;
  if (ws_size < WS_NEEDED) return;

  char* ws = (char*)d_ws;
  unsigned* sync = (unsigned*)(ws + OFF_SYNC);
  _Float16* hfrag0 = (_Float16*)(ws + OFF_HFRAG0);
  _Float16* hfragH = (_Float16*)(ws + OFF_HFRAGH);
  _Float16* emb = (_Float16*)(ws + OFF_EMB);
  _Float16* X0bf = (_Float16*)(ws + OFF_X0);
  _Float16* Wih0b = (_Float16*)(ws + OFF_WIH0);
  _Float16* Wp4 = (_Float16*)(ws + OFF_WP4);
  _Float16* Wp0 = (_Float16*)(ws + OFF_WP0);
  _Float16* embWb = (_Float16*)(ws + OFF_EMBW);
  _Float16* Winb = (_Float16*)(ws + OFF_WIN);
  _Float16* Woutb = (_Float16*)(ws + OFF_WOUT);
  _Float16* encb = (_Float16*)(ws + OFF_ENC);
  _Float16* h2all = (_Float16*)(ws + OFF_H2ALL);
  _Float16* concat = (_Float16*)(ws + OFF_CONCAT);
  _Float16* target = (_Float16*)(ws + OFF_TARGET);
  _Float16* ht = (_Float16*)(ws + OFF_HT);

  const unsigned LDSB = 155648;   // k_recur
  const unsigned LDSG = 65536;    // k_gemm256 v2: 2 slots x (A 16KB + B 16KB)
  const unsigned LDSA = 131072;   // k_attn: enc [64][1024] f16
  static int lds_set = 0;
  if (!lds_set) {
    hipFuncSetAttribute((const void*)k_recur, hipFuncAttributeMaxDynamicSharedMemorySize,
                        (int)LDSB);
    hipFuncSetAttribute((const void*)k_gemm256<0>, hipFuncAttributeMaxDynamicSharedMemorySize,
                        (int)LDSG);
    hipFuncSetAttribute((const void*)k_gemm256<1>, hipFuncAttributeMaxDynamicSharedMemorySize,
                        (int)LDSG);
    hipFuncSetAttribute((const void*)k_attn, hipFuncAttributeMaxDynamicSharedMemorySize,
                        (int)LDSA);
    lds_set = 1;
  }

  // prep: converts / packs / init
  k_conv<<<4096, 256, 0, stream>>>(embW, embWb, VV * EE / 4);
  k_conv<<<1024, 256, 0, stream>>>(Wih, Wih0b, G4 * EE / 4);       // layer-0 W_ih
  k_conv<<<512, 256, 0, stream>>>(Win, Winb, EE * EE / 4);
  k_conv<<<512, 256, 0, stream>>>(Wout, Woutb, EE * 2048 / 4);
  k_conv<<<512, 256, 0, stream>>>(enc, encb, 64 * BB * EE / 4);
  k_gather<<<NROWS, 256, 0, stream>>>(tokens, embW, emb);
  k_packw4<<<8192, 256, 0, stream>>>(Wih, Whh, Wp4);
  k_packw0<<<4096, 256, 0, stream>>>(Whh, Wp0);
  k_init<<<384, 256, 0, stream>>>(h0, hfrag0, sync);

  // X0 = emb @ Wih0^T + b_ih0 + b_hh0   -> f16 [4096,4096]
  k_gemm256<1><<<16 * 16, 1024, LDSG, stream>>>(emb, Wih0b, X0bf, NROWS, G4, EE, bih, bhh);

  // recurrence: REGULAR launch (graph-capturable); co-residency structural
  k_recur<<<256, 512, LDSB, stream>>>(Wp4, Wp0, X0bf, hfrag0, hfragH, h2all, concat,
                                      bih, bhh, c0, sync);

  // attention chain
  k_gemm<1><<<32 * 8, 256, 0, stream>>>(h2all, Winb, target, NROWS, EE, EE, nullptr, nullptr);
  k_attn<<<256, 256, LDSA, stream>>>(target, encb, concat);
  k_gemm<2><<<32 * 8, 256, 0, stream>>>(concat, Woutb, ht, NROWS, EE, 2048, nullptr, nullptr);

  // logits = ht @ embW^T + final_b  -> f32 d_out
  k_gemm256<0><<<16 * 125, 1024, LDSG, stream>>>(ht, embWb, d_out, NROWS, VV, EE, finalb, nullptr);
}

// Round 13
// 1463.354 us; speedup vs baseline: 1.0409x; 1.0409x over previous
//
#include <hip/hip_runtime.h>
#include <cstdint>
#include <cstddef>

#define SEQ   128
#define BB    32
#define EE    1024
#define HH    1024
#define G4    4096
#define VV    32000
#define NROWS 4096   // SEQ*BB

typedef _Float16 h16x8 __attribute__((ext_vector_type(8)));
typedef _Float16 h16x4 __attribute__((ext_vector_type(4)));
typedef float f32x4  __attribute__((ext_vector_type(4)));

#define AS_G(p) ((const __attribute__((address_space(1))) void*)(p))
#define AS_L(p) ((__attribute__((address_space(3))) void*)(p))

__device__ __forceinline__ float sigmf(float x) { return 1.0f / (1.0f + expf(-x)); }

// ---------------- ws layout (bytes) ----------------
// hfrag = monotonic slot ring: slot s holds [3 layers][32768 f16] (196608 B).
// slots 0..2: dedicated region; slots 3..129 overlay EMB+WIH0+TARGET (dead
// during the recurrence).
#define OFF_SYNC    0ull                      // pad[64] + arrive[256] strided 128B
#define OFF_HFRAG0  40960ull                  // 3 slots  * 196608 = 589824
#define OFF_EMB     630784ull                 // [4096][1024] f16   (8388608)
#define OFF_WIH0    9019392ull                // [4096][1024] f16   (8388608)
#define OFF_TARGET  17408000ull               // [4096][1024] f16   (8388608)
#define OFF_HT      25796608ull               // [4096][1024] f16   (8388608)
#define OFF_HFRAGH  630784ull                 // 127 slots * 196608 (overlay)
#define OFF_X0      34185216ull               // [4096][4096] f16   (33554432)
#define OFF_WP4     67739648ull               // 256 wg * 65536 f16 (33554432)
#define OFF_WP0     101294080ull              // 256 wg * 16384 f16 (8388608)
#define OFF_EMBW    109682688ull              // [32000][1024] f16  (65536000)
#define OFF_WIN     175218688ull              // [1024][1024] f16   (2097152)
#define OFF_WOUT    177315840ull              // [1024][2048] f16   (4194304)
#define OFF_ENC     181510144ull              // [64][32][1024] f16 (4194304)
#define OFF_H2ALL   185704448ull              // [4096][1024] f16   (8388608)
#define OFF_CONCAT  194093056ull              // [4096][2048] f16   (16777216)
#define WS_NEEDED   210870272ull

// ---------------- f32 -> f16 convert (vectorized, grid-stride) ----------------
__global__ __launch_bounds__(256) void k_conv(const float* __restrict__ s,
                                              _Float16* __restrict__ d, int n4) {
  int i = blockIdx.x * blockDim.x + threadIdx.x;
  int st = gridDim.x * blockDim.x;
  for (; i < n4; i += st) {
    float4 v = ((const float4*)s)[i];
    h16x4 o; o[0] = (_Float16)v.x; o[1] = (_Float16)v.y; o[2] = (_Float16)v.z; o[3] = (_Float16)v.w;
    ((h16x4*)d)[i] = o;
  }
}

// ---------------- embedding gather -> f16 ----------------
__global__ __launch_bounds__(256) void k_gather(const int* __restrict__ tok,
                                                const float* __restrict__ embW,
                                                _Float16* __restrict__ emb) {
  int row = blockIdx.x;                 // row = t*32+b
  int t = tok[row];
  float4 v = ((const float4*)(embW + (size_t)t * EE))[threadIdx.x];
  h16x4 o; o[0] = (_Float16)v.x; o[1] = (_Float16)v.y; o[2] = (_Float16)v.z; o[3] = (_Float16)v.w;
  ((h16x4*)(emb + (size_t)row * EE))[threadIdx.x] = o;
}

// ---------------- pack 4 LDS-resident matrices (Wih1,Whh1,Wih2,Whh2) ----------------
// wg w owns hidden units 4*wp..4*wp+3 with wp=(w&7)*32+(w>>3)  (XCD-local X0 lines)
__global__ __launch_bounds__(256) void k_packw4(const float* __restrict__ Wih,
                                                const float* __restrict__ Whh,
                                                _Float16* __restrict__ out) {
  int i = blockIdx.x * blockDim.x + threadIdx.x;
  int st = gridDim.x * blockDim.x;
  const int total = 256 * 65536;
  for (; i < total; i += st) {
    int w = i >> 16, rem = i & 65535;
    int wp = (w & 7) * 32 + (w >> 3);
    int mat = rem >> 14, jj = (rem >> 10) & 15, k = rem & 1023;
    int layer = 1 + (mat >> 1), isHH = mat & 1;
    int row = ((jj >> 2) << 10) + (wp << 2) + (jj & 3);
    int ks = k ^ ((jj & 7) << 3);
    const float* src = (isHH ? Whh : Wih) + (size_t)layer * G4 * 1024 + (size_t)row * 1024 + ks;
    out[i] = (_Float16)(*src);
  }
}

// ---------------- pack Whh0 fragment-linear: [w][ks 0..31][lane 0..63][e 0..7] ----------------
__global__ __launch_bounds__(256) void k_packw0(const float* __restrict__ Whh,
                                                _Float16* __restrict__ out) {
  int i = blockIdx.x * blockDim.x + threadIdx.x;
  int st = gridDim.x * blockDim.x;
  const int total = 256 * 16384;
  for (; i < total; i += st) {
    int w = i >> 14, rem = i & 16383;
    int wp = (w & 7) * 32 + (w >> 3);
    int ks = rem >> 9, lane = (rem >> 3) & 63, e = rem & 7;
    int jj = lane & 15, q = lane >> 4;
    int row = ((jj >> 2) << 10) + (wp << 2) + (jj & 3);
    int k = ks * 32 + q * 8 + e;
    out[i] = (_Float16)Whh[(size_t)row * 1024 + k];   // layer 0
  }
}

// ---------------- init: sync flags + initial h into slots 0..2 ----------------
__global__ __launch_bounds__(256) void k_init(const float* __restrict__ h0,
                                              _Float16* __restrict__ hfrag0,
                                              unsigned* __restrict__ sync) {
  int i = blockIdx.x * blockDim.x + threadIdx.x;
  if (i < 64 + 8192) sync[i] = 0u;   // pad + arrive (strided)
  if (i >= 3 * BB * HH) return;
  int l = i >> 15, rem = i & 32767;
  int b = rem >> 10, n = rem & 1023;
  int tbb = b >> 4, ks = n >> 5, q = (n >> 3) & 3, e = n & 7;
  int lane2 = (b & 15) | (q << 4);
  hfrag0[(size_t)l * 131072 + ((size_t)(tbb * 32 + ks) * 64 + lane2) * 8 + e] =
      (_Float16)h0[i];
}

// ---------------- generic 128x128 BT GEMM (A[M,K] f16, B[N,K] f16) ----------------
// EPI: 1 = f16 ; 2 = f16(tanh)   (big GEMMs use k_gemm256)
template <int EPI>
__global__ __launch_bounds__(256) void k_gemm(const _Float16* __restrict__ A,
                                              const _Float16* __restrict__ B,
                                              void* __restrict__ C, int M, int N, int K,
                                              const float* __restrict__ bias1,
                                              const float* __restrict__ bias2) {
  __shared__ _Float16 As[2][128 * 32];
  __shared__ _Float16 Bs[2][128 * 32];
  const int ntn = N / 128;
  const int nwg = gridDim.x;
  const int bid = (blockIdx.x & 7) * (nwg >> 3) + (blockIdx.x >> 3);
  const int tm = bid / ntn, tn = bid % ntn;
  const int tid = threadIdx.x, lane = tid & 63;
  const int wv = tid >> 6, wr = wv >> 1, wc = wv & 1;
  f32x4 acc[4][4] = {};

  auto stage = [&](int buf, int k0) {
#pragma unroll
    for (int i = 0; i < 2; ++i) {
      int eo = (i * 256 + tid) * 8;
      int r = eo >> 5, c = eo & 31;
      __builtin_amdgcn_global_load_lds(AS_G(A + (size_t)(tm * 128 + r) * K + k0 + c),
                                       AS_L(&As[buf][eo]), 16, 0, 0);
      __builtin_amdgcn_global_load_lds(AS_G(B + (size_t)(tn * 128 + r) * K + k0 + c),
                                       AS_L(&Bs[buf][eo]), 16, 0, 0);
    }
  };
  stage(0, 0);
  __syncthreads();
  const int nk = K / 32;
  for (int kt = 0; kt < nk; ++kt) {
    if (kt + 1 < nk) stage((kt + 1) & 1, (kt + 1) * 32);
    const int buf = kt & 1;
    h16x8 af[4], bfr[4];
#pragma unroll
    for (int mi = 0; mi < 4; ++mi)
      af[mi] = *(const h16x8*)&As[buf][(wr * 64 + mi * 16 + (lane & 15)) * 32 + (lane >> 4) * 8];
#pragma unroll
    for (int ni = 0; ni < 4; ++ni)
      bfr[ni] = *(const h16x8*)&Bs[buf][(wc * 64 + ni * 16 + (lane & 15)) * 32 + (lane >> 4) * 8];
#pragma unroll
    for (int mi = 0; mi < 4; ++mi)
#pragma unroll
      for (int ni = 0; ni < 4; ++ni)
        acc[mi][ni] = __builtin_amdgcn_mfma_f32_16x16x32_f16(af[mi], bfr[ni], acc[mi][ni], 0, 0, 0);
    __syncthreads();
  }
  const int rbase = tm * 128 + wr * 64;
  const int cbase = tn * 128 + wc * 64;
#pragma unroll
  for (int mi = 0; mi < 4; ++mi) {
#pragma unroll
    for (int ni = 0; ni < 4; ++ni) {
#pragma unroll
      for (int r = 0; r < 4; ++r) {
        int mm = rbase + mi * 16 + (lane >> 4) * 4 + r;
        int nn = cbase + ni * 16 + (lane & 15);
        float v = acc[mi][ni][r];
        if (EPI == 1) {
          ((_Float16*)C)[(size_t)mm * N + nn] = (_Float16)v;
        } else {
          ((_Float16*)C)[(size_t)mm * N + nn] = (_Float16)tanhf(v);
        }
      }
    }
  }
}

// ---------------- 256x256 BT GEMM, 3-slot LDS ring + counted vmcnt (T4) ----------------
// (R11-proven structure: 512 thr, 8 waves, depth-2 prefetch, vmcnt(4).)
// tn-MAJOR block mapping: consecutive bids within an XCD share the B panel ->
// B (embW, 64MB) per-XCD traffic drops to ~16 L2-resident panels (was 64MB/XCD).
// EPI: 0 = f32 + bias1 ; 1 = f16 + bias1 + bias2
template <int EPI>
__global__ __launch_bounds__(512, 2) void k_gemm256(const _Float16* __restrict__ A,
                                                    const _Float16* __restrict__ B,
                                                    void* __restrict__ C, int M, int N, int K,
                                                    const float* __restrict__ bias1,
                                                    const float* __restrict__ bias2) {
  extern __shared__ char glds[];
  _Float16* Asl = (_Float16*)glds;                     // [3][256*32]
  _Float16* Bsl = (_Float16*)(glds + 3 * 8192 * 2);    // [3][256*32]
  const int ntm = M / 256;
  const int nwg = gridDim.x;
  const int bid = (blockIdx.x & 7) * (nwg >> 3) + (blockIdx.x >> 3);
  const int tm = bid % ntm, tn = bid / ntm;            // tn-major
  const int tid = threadIdx.x, lane = tid & 63;
  const int wid = tid >> 6, wm = wid >> 2, wn = wid & 3;
  const int fr = lane & 15, fc = lane >> 4;
  const int srow0 = tid >> 2, sg = tid & 3;    // staging: row within 128-half, granule

  f32x4 acc[8][4] = {};
  const int nt = K / 32;

  auto stage = [&](int t) {
    const int slot = t % 3;
    const size_t kof = (size_t)t * 32 + sg * 8;
#pragma unroll
    for (int r = 0; r < 2; ++r) {
      int row = r * 128 + srow0;
      __builtin_amdgcn_global_load_lds(AS_G(A + (size_t)(tm * 256 + row) * K + kof),
                                       AS_L(&Asl[slot * 8192 + row * 32 + sg * 8]), 16, 0, 0);
    }
#pragma unroll
    for (int r = 0; r < 2; ++r) {
      int row = r * 128 + srow0;
      __builtin_amdgcn_global_load_lds(AS_G(B + (size_t)(tn * 256 + row) * K + kof),
                                       AS_L(&Bsl[slot * 8192 + row * 32 + sg * 8]), 16, 0, 0);
    }
  };

  stage(0);
  stage(1);
  asm volatile("s_waitcnt vmcnt(4)" ::: "memory");   // tile 0 landed (mine)
  asm volatile("s_barrier" ::: "memory");            // tile 0 landed (all waves)

  for (int t = 0; t < nt; ++t) {
    if (t + 2 < nt) {
      stage(t + 2);
      asm volatile("s_waitcnt vmcnt(4)" ::: "memory");   // tile t+1 landed; t+2 in flight
    } else {
      asm volatile("s_waitcnt vmcnt(0)" ::: "memory");   // tail drain
    }
    asm volatile("s_barrier" ::: "memory");              // globalize tile t+1 / protect ring
    const int slot = t % 3;
    const _Float16* as = &Asl[slot * 8192];
    const _Float16* bs = &Bsl[slot * 8192];
    h16x8 af[8], bf[4];
#pragma unroll
    for (int mi = 0; mi < 8; ++mi)
      af[mi] = *(const h16x8*)&as[(wm * 128 + mi * 16 + fr) * 32 + fc * 8];
#pragma unroll
    for (int ni = 0; ni < 4; ++ni)
      bf[ni] = *(const h16x8*)&bs[(wn * 64 + ni * 16 + fr) * 32 + fc * 8];
    __builtin_amdgcn_s_setprio(1);
#pragma unroll
    for (int mi = 0; mi < 8; ++mi)
#pragma unroll
      for (int ni = 0; ni < 4; ++ni)
        acc[mi][ni] = __builtin_amdgcn_mfma_f32_16x16x32_f16(af[mi], bf[ni], acc[mi][ni], 0, 0, 0);
    __builtin_amdgcn_s_setprio(0);
    asm volatile("s_barrier" ::: "memory");   // my reads of slot done before others restage it
  }

  const int rbase = tm * 256 + wm * 128;
  const int cbase = tn * 256 + wn * 64;
#pragma unroll
  for (int mi = 0; mi < 8; ++mi) {
#pragma unroll
    for (int ni = 0; ni < 4; ++ni) {
#pragma unroll
      for (int r = 0; r < 4; ++r) {
        int mm = rbase + mi * 16 + fc * 4 + r;
        int nn = cbase + ni * 16 + fr;
        float v = acc[mi][ni][r];
        if (EPI == 0) {
          ((float*)C)[(size_t)mm * N + nn] = v + bias1[nn];
        } else {
          ((_Float16*)C)[(size_t)mm * N + nn] = (_Float16)(v + bias1[nn] + bias2[nn]);
        }
      }
    }
  }
}

// ---------------- persistent pipelined LSTM recurrence (R11-proven, unchanged) ----------------
__global__ __launch_bounds__(512) void k_recur(const _Float16* __restrict__ Wp4,
                                               const _Float16* __restrict__ Wp0,
                                               const _Float16* __restrict__ X0bf,
                                               _Float16* __restrict__ hfrag0,
                                               _Float16* __restrict__ hfragH,
                                               _Float16* __restrict__ h2all,
                                               _Float16* __restrict__ concat,
                                               const float* __restrict__ bih,
                                               const float* __restrict__ bhh,
                                               const float* __restrict__ c0p,
                                               unsigned* __restrict__ sync) {
  extern __shared__ char lds[];
  _Float16* ldsW = (_Float16*)lds;                 // 65536 f16
  float* redbuf = (float*)(lds + 131072);          // [3][3][2][256]
  _Float16* hstage = (_Float16*)(lds + 131072);    // [3][128] (reused after redbuf)
  float* gbuf = (float*)(lds + 149504);            // [3][32][16]
  unsigned* arrive = sync + 64;                    // strided: arrive[w*32]

  const int w = blockIdx.x;
  const int wp = (w & 7) * 32 + (w >> 3);          // XCD-local unit-block remap
  const int tid = threadIdx.x, lane = tid & 63, wv = tid >> 6;
  const int tb = wv & 1, kq = wv >> 1;
  const int row = (lane >> 4) * 4, col = lane & 15;

  for (int i = 0; i < 16; ++i) {
    int eo = (i * 512 + tid) * 8;
    *(h16x8*)&ldsW[eo] = *(const h16x8*)(Wp4 + (size_t)w * 65536 + eo);
  }
  h16x8 w0reg[8];
#pragma unroll
  for (int i = 0; i < 8; ++i)
    w0reg[i] = *(const h16x8*)(Wp0 + (size_t)w * 16384 + ((size_t)(kq * 8 + i) * 64 + lane) * 8);

  const int eb = tid >> 2, eni = tid & 3, en = wp * 4 + eni;
  float c0r = 0.f, c1r = 0.f, c2r = 0.f;
  float b1r[4] = {0, 0, 0, 0}, b2r[4] = {0, 0, 0, 0};
  if (tid < 128) {
    c0r = c0p[0 * BB * HH + eb * HH + en];
    c1r = c0p[1 * BB * HH + eb * HH + en];
    c2r = c0p[2 * BB * HH + eb * HH + en];
#pragma unroll
    for (int g = 0; g < 4; ++g) {
      b1r[g] = bih[1 * G4 + g * 1024 + en] + bhh[1 * G4 + g * 1024 + en];
      b2r[g] = bih[2 * G4 + g * 1024 + en] + bhh[2 * G4 + g * 1024 + en];
    }
  }
  const int pk_l = tid >> 5, pk_r = tid & 31;
  const size_t pk_idx = ((size_t)(((pk_r >> 4) * 32 + (wp >> 3)) * 64 + (pk_r & 15) +
                                  (((wp >> 1) & 3) << 4))) * 8 + 4 * (wp & 1);
  __syncthreads();

  for (int tau = 0; tau < 130; ++tau) {
    const _Float16* rb = (tau < 3) ? (hfrag0 + (size_t)tau * 98304)
                                   : (hfragH + (size_t)(tau - 3) * 98304);
    _Float16* wb = (tau + 1 < 3) ? (hfrag0 + (size_t)(tau + 1) * 98304)
                                 : (hfragH + (size_t)(tau - 2) * 98304);
    const _Float16* h0r = rb;
    const _Float16* h1r = rb + 32768;
    const _Float16* h2r = rb + 65536;

    h16x8 a0[8], a1[8], a2[8];
#pragma unroll
    for (int i = 0; i < 8; ++i) {
      int ks = kq * 8 + i;
      size_t off = ((size_t)(tb * 32 + ks) * 64 + lane) * 8;
      a0[i] = *(const h16x8*)(h0r + off);
      a1[i] = *(const h16x8*)(h1r + off);
      a2[i] = *(const h16x8*)(h2r + off);
    }
    float xg0 = 0.f, xg1 = 0.f, xg2 = 0.f, xg3 = 0.f;
    if (tid < 128 && tau < 128) {
      size_t xb = ((size_t)(tau * BB + eb)) * G4 + en;
      xg0 = (float)X0bf[xb];        xg1 = (float)X0bf[xb + 1024];
      xg2 = (float)X0bf[xb + 2048]; xg3 = (float)X0bf[xb + 3072];
    }
    f32x4 acc0 = {}, acc1 = {}, acc2 = {};
#pragma unroll
    for (int i = 0; i < 8; ++i) {
      int ks = kq * 8 + i;
      int jj = lane & 15, q = lane >> 4;
      int kk = (ks * 32 + q * 8) ^ ((jj & 7) << 3);
      const h16x8 bw1i = *(const h16x8*)&ldsW[0 * 16384 + jj * 1024 + kk];
      const h16x8 bw1h = *(const h16x8*)&ldsW[1 * 16384 + jj * 1024 + kk];
      const h16x8 bw2i = *(const h16x8*)&ldsW[2 * 16384 + jj * 1024 + kk];
      const h16x8 bw2h = *(const h16x8*)&ldsW[3 * 16384 + jj * 1024 + kk];
      acc0 = __builtin_amdgcn_mfma_f32_16x16x32_f16(a0[i], w0reg[i], acc0, 0, 0, 0);
      acc1 = __builtin_amdgcn_mfma_f32_16x16x32_f16(a0[i], bw1i, acc1, 0, 0, 0);
      acc1 = __builtin_amdgcn_mfma_f32_16x16x32_f16(a1[i], bw1h, acc1, 0, 0, 0);
      acc2 = __builtin_amdgcn_mfma_f32_16x16x32_f16(a1[i], bw2i, acc2, 0, 0, 0);
      acc2 = __builtin_amdgcn_mfma_f32_16x16x32_f16(a2[i], bw2h, acc2, 0, 0, 0);
    }
    if (kq >= 1) {
      int s = kq - 1;
#pragma unroll
      for (int r = 0; r < 4; ++r) {
        redbuf[((0 * 3 + s) * 2 + tb) * 256 + (row + r) * 16 + col] = acc0[r];
        redbuf[((1 * 3 + s) * 2 + tb) * 256 + (row + r) * 16 + col] = acc1[r];
        redbuf[((2 * 3 + s) * 2 + tb) * 256 + (row + r) * 16 + col] = acc2[r];
      }
    }
    __syncthreads();
    if (kq == 0) {
#pragma unroll
      for (int r = 0; r < 4; ++r) {
        float v0 = acc0[r], v1 = acc1[r], v2 = acc2[r];
#pragma unroll
        for (int s = 0; s < 3; ++s) {
          v0 += redbuf[((0 * 3 + s) * 2 + tb) * 256 + (row + r) * 16 + col];
          v1 += redbuf[((1 * 3 + s) * 2 + tb) * 256 + (row + r) * 16 + col];
          v2 += redbuf[((2 * 3 + s) * 2 + tb) * 256 + (row + r) * 16 + col];
        }
        gbuf[(0 * 32 + tb * 16 + row + r) * 16 + col] = v0;
        gbuf[(1 * 32 + tb * 16 + row + r) * 16 + col] = v1;
        gbuf[(2 * 32 + tb * 16 + row + r) * 16 + col] = v2;
      }
    }
    __syncthreads();
    if (tid < 128) {
      if (tau < 128) {
        float gi = gbuf[(0 * 32 + eb) * 16 + eni] + xg0;
        float gf = gbuf[(0 * 32 + eb) * 16 + 4 + eni] + xg1;
        float gg = gbuf[(0 * 32 + eb) * 16 + 8 + eni] + xg2;
        float go = gbuf[(0 * 32 + eb) * 16 + 12 + eni] + xg3;
        c0r = sigmf(gf) * c0r + sigmf(gi) * tanhf(gg);
        hstage[0 * 128 + tid] = (_Float16)(sigmf(go) * tanhf(c0r));
      }
      if (tau >= 1 && tau < 129) {
        float gi = gbuf[(1 * 32 + eb) * 16 + eni] + b1r[0];
        float gf = gbuf[(1 * 32 + eb) * 16 + 4 + eni] + b1r[1];
        float gg = gbuf[(1 * 32 + eb) * 16 + 8 + eni] + b1r[2];
        float go = gbuf[(1 * 32 + eb) * 16 + 12 + eni] + b1r[3];
        c1r = sigmf(gf) * c1r + sigmf(gi) * tanhf(gg);
        hstage[1 * 128 + tid] = (_Float16)(sigmf(go) * tanhf(c1r));
      }
      if (tau >= 2) {
        float gi = gbuf[(2 * 32 + eb) * 16 + eni] + b2r[0];
        float gf = gbuf[(2 * 32 + eb) * 16 + 4 + eni] + b2r[1];
        float gg = gbuf[(2 * 32 + eb) * 16 + 8 + eni] + b2r[2];
        float go = gbuf[(2 * 32 + eb) * 16 + 12 + eni] + b2r[3];
        c2r = sigmf(gf) * c2r + sigmf(gi) * tanhf(gg);
        float h = sigmf(go) * tanhf(c2r);
        _Float16 hb = (_Float16)h;
        hstage[2 * 128 + tid] = hb;
        int t2 = tau - 2;
        h2all[(size_t)(t2 * BB + eb) * HH + en] = hb;
        concat[(size_t)(t2 * BB + eb) * 2048 + 1024 + en] = hb;
      }
    }
    __syncthreads();
    {
      bool act = (tid < 96) &&
                 ((pk_l == 0) ? (tau < 128)
                  : (pk_l == 1) ? (tau >= 1 && tau < 129)
                                : (tau >= 2 && tau < 129));
      if (act) {
        unsigned long long v = *(const unsigned long long*)&hstage[pk_l * 128 + pk_r * 4];
        __hip_atomic_store(
            (unsigned long long*)(wb + (size_t)pk_l * 32768 + pk_idx), v,
            __ATOMIC_RELAXED, __HIP_MEMORY_SCOPE_AGENT);
      }
      asm volatile("s_waitcnt vmcnt(0)" ::: "memory");
    }
    __syncthreads();
    if (tid == 0)
      __hip_atomic_store(&arrive[w * 32], (unsigned)(tau + 1), __ATOMIC_RELAXED,
                         __HIP_MEMORY_SCOPE_AGENT);
    if (tau < 129) {
      if (tid < 64) {
        for (;;) {
          bool ok = true;
#pragma unroll
          for (int j = 0; j < 4; ++j) {
            unsigned v = __hip_atomic_load(&arrive[(tid * 4 + j) * 32], __ATOMIC_RELAXED,
                                           __HIP_MEMORY_SCOPE_AGENT);
            ok &= (v >= (unsigned)(tau + 1));
          }
          if (__all(ok)) break;
          __builtin_amdgcn_s_sleep(1);
        }
        asm volatile("" ::: "memory");
      }
      __syncthreads();
    }
  }
}

// ---------------- fused scores+softmax+weighted-context per (t,b) (R11-proven) ----------------
__global__ __launch_bounds__(256) void k_attn(const _Float16* __restrict__ target,
                                              const _Float16* __restrict__ encb,
                                              _Float16* __restrict__ concat) {
  __shared__ float sc[64];
  __shared__ float att[64];
  int m = blockIdx.x, b = m & 31;
  int tid = threadIdx.x, lane = tid & 63, wv = tid >> 6;
  const h16x8* tp = (const h16x8*)(target + (size_t)m * EE + lane * 16);
  h16x8 tg0 = tp[0], tg1 = tp[1];
  for (int si = 0; si < 16; ++si) {
    int s = wv * 16 + si;
    const h16x8* ep = (const h16x8*)(encb + ((size_t)s * BB + b) * EE + lane * 16);
    h16x8 e0 = ep[0], e1 = ep[1];
    float a = 0.f;
#pragma unroll
    for (int j = 0; j < 8; ++j) a += (float)e0[j] * (float)tg0[j];
#pragma unroll
    for (int j = 0; j < 8; ++j) a += (float)e1[j] * (float)tg1[j];
#pragma unroll
    for (int off = 32; off >= 1; off >>= 1) a += __shfl_xor(a, off);
    if (lane == 0) sc[s] = a;
  }
  __syncthreads();
  if (wv == 0) {
    float v = sc[lane], mx = v;
#pragma unroll
    for (int off = 32; off >= 1; off >>= 1) mx = fmaxf(mx, __shfl_xor(mx, off));
    float e = expf(v - mx), sm = e;
#pragma unroll
    for (int off = 32; off >= 1; off >>= 1) sm += __shfl_xor(sm, off);
    att[lane] = e / sm;
  }
  __syncthreads();
  int e4 = tid * 4;
  float a0 = 0, a1 = 0, a2 = 0, a3 = 0;
  for (int s = 0; s < 64; ++s) {
    float wgt = att[s];
    h16x4 ev = *(const h16x4*)(encb + ((size_t)s * BB + b) * EE + e4);
    a0 += wgt * (float)ev[0]; a1 += wgt * (float)ev[1];
    a2 += wgt * (float)ev[2]; a3 += wgt * (float)ev[3];
  }
  h16x4 o; o[0] = (_Float16)a0; o[1] = (_Float16)a1; o[2] = (_Float16)a2; o[3] = (_Float16)a3;
  *(h16x4*)(concat + (size_t)m * 2048 + e4) = o;
}

// ---------------- host ----------------
extern "C" void kernel_launch(void* const* d_in, const int* in_sizes, int n_in,
                              void* d_out, int out_size, void* d_ws, size_t ws_size,
                              hipStream_t stream) {
  const int* tokens = (const int*)d_in[0];
  const float* embW = (const float*)d_in[1];
  const float* Wih = (const float*)d_in[2];
  const float* Whh = (const float*)d_in[3];
  const float* bih = (const float*)d_in[4];
  const float* bhh = (const float*)d_in[5];
  const float* Win = (const float*)d_in[6];
  const float* Wout = (const float*)d_in[7];
  const float* finalb = (const float*)d_in[8];
  const float* enc = (const float*)d_in[9];
  const float* h0 = (const float*)d_in[10];
  const float* c0 = (const float*)d_in[11];
  (void)in_sizes; (void)n_in; (void)out_size;
  if (ws_size < WS_NEEDED) return;

  char* ws = (char*)d_ws;
  unsigned* sync = (unsigned*)(ws + OFF_SYNC);
  _Float16* hfrag0 = (_Float16*)(ws + OFF_HFRAG0);
  _Float16* hfragH = (_Float16*)(ws + OFF_HFRAGH);
  _Float16* emb = (_Float16*)(ws + OFF_EMB);
  _Float16* X0bf = (_Float16*)(ws + OFF_X0);
  _Float16* Wih0b = (_Float16*)(ws + OFF_WIH0);
  _Float16* Wp4 = (_Float16*)(ws + OFF_WP4);
  _Float16* Wp0 = (_Float16*)(ws + OFF_WP0);
  _Float16* embWb = (_Float16*)(ws + OFF_EMBW);
  _Float16* Winb = (_Float16*)(ws + OFF_WIN);
  _Float16* Woutb = (_Float16*)(ws + OFF_WOUT);
  _Float16* encb = (_Float16*)(ws + OFF_ENC);
  _Float16* h2all = (_Float16*)(ws + OFF_H2ALL);
  _Float16* concat = (_Float16*)(ws + OFF_CONCAT);
  _Float16* target = (_Float16*)(ws + OFF_TARGET);
  _Float16* ht = (_Float16*)(ws + OFF_HT);

  const unsigned LDSB = 155648;   // k_recur
  const unsigned LDSG = 98304;    // k_gemm256: 3 slots x (A 16KB + B 16KB)
  static int lds_set = 0;
  if (!lds_set) {
    hipFuncSetAttribute((const void*)k_recur, hipFuncAttributeMaxDynamicSharedMemorySize,
                        (int)LDSB);
    hipFuncSetAttribute((const void*)k_gemm256<0>, hipFuncAttributeMaxDynamicSharedMemorySize,
                        (int)LDSG);
    hipFuncSetAttribute((const void*)k_gemm256<1>, hipFuncAttributeMaxDynamicSharedMemorySize,
                        (int)LDSG);
    lds_set = 1;
  }

  // prep: converts / packs / init
  k_conv<<<4096, 256, 0, stream>>>(embW, embWb, VV * EE / 4);
  k_conv<<<1024, 256, 0, stream>>>(Wih, Wih0b, G4 * EE / 4);       // layer-0 W_ih
  k_conv<<<512, 256, 0, stream>>>(Win, Winb, EE * EE / 4);
  k_conv<<<512, 256, 0, stream>>>(Wout, Woutb, EE * 2048 / 4);
  k_conv<<<512, 256, 0, stream>>>(enc, encb, 64 * BB * EE / 4);
  k_gather<<<NROWS, 256, 0, stream>>>(tokens, embW, emb);
  k_packw4<<<8192, 256, 0, stream>>>(Wih, Whh, Wp4);
  k_packw0<<<4096, 256, 0, stream>>>(Whh, Wp0);
  k_init<<<384, 256, 0, stream>>>(h0, hfrag0, sync);

  // X0 = emb @ Wih0^T + b_ih0 + b_hh0   -> f16 [4096,4096]
  k_gemm256<1><<<16 * 16, 512, LDSG, stream>>>(emb, Wih0b, X0bf, NROWS, G4, EE, bih, bhh);

  // recurrence: REGULAR launch (graph-capturable); co-residency structural
  k_recur<<<256, 512, LDSB, stream>>>(Wp4, Wp0, X0bf, hfrag0, hfragH, h2all, concat,
                                      bih, bhh, c0, sync);

  // attention chain
  k_gemm<1><<<32 * 8, 256, 0, stream>>>(h2all, Winb, target, NROWS, EE, EE, nullptr, nullptr);
  k_attn<<<NROWS, 256, 0, stream>>>(target, encb, concat);
  k_gemm<2><<<32 * 8, 256, 0, stream>>>(concat, Woutb, ht, NROWS, EE, 2048, nullptr, nullptr);

  // logits = ht @ embW^T + final_b  -> f32 d_out
  k_gemm256<0><<<16 * 125, 512, LDSG, stream>>>(ht, embWb, d_out, NROWS, VV, EE, finalb, nullptr);
}

// Round 14
// 1412.972 us; speedup vs baseline: 1.0780x; 1.0357x over previous
//
#include <hip/hip_runtime.h>
#include <cstdint>
#include <cstddef>

#define SEQ   128
#define BB    32
#define EE    1024
#define HH    1024
#define G4    4096
#define VV    32000
#define NROWS 4096   // SEQ*BB

typedef _Float16 h16x8 __attribute__((ext_vector_type(8)));
typedef _Float16 h16x4 __attribute__((ext_vector_type(4)));
typedef float f32x4  __attribute__((ext_vector_type(4)));

#define AS_G(p) ((const __attribute__((address_space(1))) void*)(p))
#define AS_L(p) ((__attribute__((address_space(3))) void*)(p))

__device__ __forceinline__ float sigmf(float x) { return 1.0f / (1.0f + expf(-x)); }

// ---------------- ws layout (bytes) ----------------
// hfrag = monotonic slot ring: slot s holds [3 layers][32768 f16] (196608 B).
// slots 0..2: dedicated region; slots 3..129 overlay EMB+WIH0+TARGET (dead
// during the recurrence).
#define OFF_SYNC    0ull                      // pad[64] + arrive[256] strided 128B
#define OFF_HFRAG0  40960ull                  // 3 slots  * 196608 = 589824
#define OFF_EMB     630784ull                 // [4096][1024] f16   (8388608)
#define OFF_WIH0    9019392ull                // [4096][1024] f16   (8388608)
#define OFF_TARGET  17408000ull               // [4096][1024] f16   (8388608)
#define OFF_HT      25796608ull               // [4096][1024] f16   (8388608)
#define OFF_HFRAGH  630784ull                 // 127 slots * 196608 (overlay)
#define OFF_X0      34185216ull               // [4096][4096] f16   (33554432)
#define OFF_WP4     67739648ull               // 256 wg * 65536 f16 (33554432)
#define OFF_WP0     101294080ull              // 256 wg * 16384 f16 (8388608)
#define OFF_EMBW    109682688ull              // [32000][1024] f16  (65536000)
#define OFF_WIN     175218688ull              // [1024][1024] f16   (2097152)
#define OFF_WOUT    177315840ull              // [1024][2048] f16   (4194304)
#define OFF_ENC     181510144ull              // [64][32][1024] f16 (4194304)
#define OFF_H2ALL   185704448ull              // [4096][1024] f16   (8388608)
#define OFF_CONCAT  194093056ull              // [4096][2048] f16   (16777216)
#define WS_NEEDED   210870272ull

// ---------------- merged f32 -> f16 convert: 5 segments in ONE launch ----------------
__global__ __launch_bounds__(256) void k_convall(const float* __restrict__ s0, _Float16* d0, int n0,
                                                 const float* __restrict__ s1, _Float16* d1, int n1,
                                                 const float* __restrict__ s2, _Float16* d2, int n2,
                                                 const float* __restrict__ s3, _Float16* d3, int n3,
                                                 const float* __restrict__ s4, _Float16* d4, int n4) {
  const int base = blockIdx.x * blockDim.x + threadIdx.x;
  const int st = gridDim.x * blockDim.x;
#pragma unroll 1
  for (int seg = 0; seg < 5; ++seg) {
    const float* s = seg == 0 ? s0 : seg == 1 ? s1 : seg == 2 ? s2 : seg == 3 ? s3 : s4;
    _Float16* d = seg == 0 ? d0 : seg == 1 ? d1 : seg == 2 ? d2 : seg == 3 ? d3 : d4;
    int n = seg == 0 ? n0 : seg == 1 ? n1 : seg == 2 ? n2 : seg == 3 ? n3 : n4;
    for (int i = base; i < n; i += st) {
      float4 v = ((const float4*)s)[i];
      h16x4 o; o[0] = (_Float16)v.x; o[1] = (_Float16)v.y; o[2] = (_Float16)v.z; o[3] = (_Float16)v.w;
      ((h16x4*)d)[i] = o;
    }
  }
}

// ---------------- embedding gather from f16 table ----------------
__global__ __launch_bounds__(256) void k_gather(const int* __restrict__ tok,
                                                const _Float16* __restrict__ embWb,
                                                _Float16* __restrict__ emb) {
  int row = blockIdx.x;                 // row = t*32+b
  int t = tok[row];
  h16x4 v = ((const h16x4*)(embWb + (size_t)t * EE))[threadIdx.x];
  ((h16x4*)(emb + (size_t)row * EE))[threadIdx.x] = v;
}

// ---------------- pack 4 LDS-resident matrices (Wih1,Whh1,Wih2,Whh2) ----------------
// wg w owns hidden units 4*wp..4*wp+3 with wp=(w&7)*32+(w>>3)  (XCD-local X0 lines)
__global__ __launch_bounds__(256) void k_packw4(const float* __restrict__ Wih,
                                                const float* __restrict__ Whh,
                                                _Float16* __restrict__ out) {
  int i = blockIdx.x * blockDim.x + threadIdx.x;
  int st = gridDim.x * blockDim.x;
  const int total = 256 * 65536;
  for (; i < total; i += st) {
    int w = i >> 16, rem = i & 65535;
    int wp = (w & 7) * 32 + (w >> 3);
    int mat = rem >> 14, jj = (rem >> 10) & 15, k = rem & 1023;
    int layer = 1 + (mat >> 1), isHH = mat & 1;
    int row = ((jj >> 2) << 10) + (wp << 2) + (jj & 3);
    int ks = k ^ ((jj & 7) << 3);
    const float* src = (isHH ? Whh : Wih) + (size_t)layer * G4 * 1024 + (size_t)row * 1024 + ks;
    out[i] = (_Float16)(*src);
  }
}

// ---------------- pack Whh0 fragment-linear: [w][ks 0..31][lane 0..63][e 0..7] ----------------
__global__ __launch_bounds__(256) void k_packw0(const float* __restrict__ Whh,
                                                _Float16* __restrict__ out) {
  int i = blockIdx.x * blockDim.x + threadIdx.x;
  int st = gridDim.x * blockDim.x;
  const int total = 256 * 16384;
  for (; i < total; i += st) {
    int w = i >> 14, rem = i & 16383;
    int wp = (w & 7) * 32 + (w >> 3);
    int ks = rem >> 9, lane = (rem >> 3) & 63, e = rem & 7;
    int jj = lane & 15, q = lane >> 4;
    int row = ((jj >> 2) << 10) + (wp << 2) + (jj & 3);
    int k = ks * 32 + q * 8 + e;
    out[i] = (_Float16)Whh[(size_t)row * 1024 + k];   // layer 0
  }
}

// ---------------- init: sync flags + initial h into slots 0..2 ----------------
__global__ __launch_bounds__(256) void k_init(const float* __restrict__ h0,
                                              _Float16* __restrict__ hfrag0,
                                              unsigned* __restrict__ sync) {
  int i = blockIdx.x * blockDim.x + threadIdx.x;
  if (i < 64 + 8192) sync[i] = 0u;   // pad + arrive (strided)
  if (i >= 3 * BB * HH) return;
  int l = i >> 15, rem = i & 32767;
  int b = rem >> 10, n = rem & 1023;
  int tbb = b >> 4, ks = n >> 5, q = (n >> 3) & 3, e = n & 7;
  int lane2 = (b & 15) | (q << 4);
  hfrag0[(size_t)l * 131072 + ((size_t)(tbb * 32 + ks) * 64 + lane2) * 8 + e] =
      (_Float16)h0[i];
}

// ---------------- generic 128x128 BT GEMM (A[M,K] f16, B[N,K] f16) ----------------
// EPI: 1 = f16 ; 2 = f16(tanh)   (big GEMMs use k_gemm256)
template <int EPI>
__global__ __launch_bounds__(256) void k_gemm(const _Float16* __restrict__ A,
                                              const _Float16* __restrict__ B,
                                              void* __restrict__ C, int M, int N, int K,
                                              const float* __restrict__ bias1,
                                              const float* __restrict__ bias2) {
  __shared__ _Float16 As[2][128 * 32];
  __shared__ _Float16 Bs[2][128 * 32];
  const int ntn = N / 128;
  const int nwg = gridDim.x;
  const int bid = (blockIdx.x & 7) * (nwg >> 3) + (blockIdx.x >> 3);
  const int tm = bid / ntn, tn = bid % ntn;
  const int tid = threadIdx.x, lane = tid & 63;
  const int wv = tid >> 6, wr = wv >> 1, wc = wv & 1;
  f32x4 acc[4][4] = {};

  auto stage = [&](int buf, int k0) {
#pragma unroll
    for (int i = 0; i < 2; ++i) {
      int eo = (i * 256 + tid) * 8;
      int r = eo >> 5, c = eo & 31;
      __builtin_amdgcn_global_load_lds(AS_G(A + (size_t)(tm * 128 + r) * K + k0 + c),
                                       AS_L(&As[buf][eo]), 16, 0, 0);
      __builtin_amdgcn_global_load_lds(AS_G(B + (size_t)(tn * 128 + r) * K + k0 + c),
                                       AS_L(&Bs[buf][eo]), 16, 0, 0);
    }
  };
  stage(0, 0);
  __syncthreads();
  const int nk = K / 32;
  for (int kt = 0; kt < nk; ++kt) {
    if (kt + 1 < nk) stage((kt + 1) & 1, (kt + 1) * 32);
    const int buf = kt & 1;
    h16x8 af[4], bfr[4];
#pragma unroll
    for (int mi = 0; mi < 4; ++mi)
      af[mi] = *(const h16x8*)&As[buf][(wr * 64 + mi * 16 + (lane & 15)) * 32 + (lane >> 4) * 8];
#pragma unroll
    for (int ni = 0; ni < 4; ++ni)
      bfr[ni] = *(const h16x8*)&Bs[buf][(wc * 64 + ni * 16 + (lane & 15)) * 32 + (lane >> 4) * 8];
#pragma unroll
    for (int mi = 0; mi < 4; ++mi)
#pragma unroll
      for (int ni = 0; ni < 4; ++ni)
        acc[mi][ni] = __builtin_amdgcn_mfma_f32_16x16x32_f16(af[mi], bfr[ni], acc[mi][ni], 0, 0, 0);
    __syncthreads();
  }
  const int rbase = tm * 128 + wr * 64;
  const int cbase = tn * 128 + wc * 64;
#pragma unroll
  for (int mi = 0; mi < 4; ++mi) {
#pragma unroll
    for (int ni = 0; ni < 4; ++ni) {
#pragma unroll
      for (int r = 0; r < 4; ++r) {
        int mm = rbase + mi * 16 + (lane >> 4) * 4 + r;
        int nn = cbase + ni * 16 + (lane & 15);
        float v = acc[mi][ni][r];
        if (EPI == 1) {
          ((_Float16*)C)[(size_t)mm * N + nn] = (_Float16)v;
        } else {
          ((_Float16*)C)[(size_t)mm * N + nn] = (_Float16)tanhf(v);
        }
      }
    }
  }
}

// ---------------- 256x256 BT GEMM, 3-slot LDS ring + counted vmcnt (T4) ----------------
// R11-proven: 512 thr, 8 waves, depth-2 prefetch, vmcnt(4), tm-MAJOR mapping
// (XCD swizzle then gives each XCD ~2 contiguous tm panels -> A is L2-resident).
// EPI: 0 = f32 + bias1 ; 1 = f16 + bias1 + bias2
template <int EPI>
__global__ __launch_bounds__(512, 2) void k_gemm256(const _Float16* __restrict__ A,
                                                    const _Float16* __restrict__ B,
                                                    void* __restrict__ C, int M, int N, int K,
                                                    const float* __restrict__ bias1,
                                                    const float* __restrict__ bias2) {
  extern __shared__ char glds[];
  _Float16* Asl = (_Float16*)glds;                     // [3][256*32]
  _Float16* Bsl = (_Float16*)(glds + 3 * 8192 * 2);    // [3][256*32]
  const int ntn = N / 256;
  const int nwg = gridDim.x;
  const int bid = (blockIdx.x & 7) * (nwg >> 3) + (blockIdx.x >> 3);
  const int tm = bid / ntn, tn = bid % ntn;            // tm-major (R11)
  const int tid = threadIdx.x, lane = tid & 63;
  const int wid = tid >> 6, wm = wid >> 2, wn = wid & 3;
  const int fr = lane & 15, fc = lane >> 4;
  const int srow0 = tid >> 2, sg = tid & 3;    // staging: row within 128-half, granule

  f32x4 acc[8][4] = {};
  const int nt = K / 32;

  auto stage = [&](int t) {
    const int slot = t % 3;
    const size_t kof = (size_t)t * 32 + sg * 8;
#pragma unroll
    for (int r = 0; r < 2; ++r) {
      int row = r * 128 + srow0;
      __builtin_amdgcn_global_load_lds(AS_G(A + (size_t)(tm * 256 + row) * K + kof),
                                       AS_L(&Asl[slot * 8192 + row * 32 + sg * 8]), 16, 0, 0);
    }
#pragma unroll
    for (int r = 0; r < 2; ++r) {
      int row = r * 128 + srow0;
      __builtin_amdgcn_global_load_lds(AS_G(B + (size_t)(tn * 256 + row) * K + kof),
                                       AS_L(&Bsl[slot * 8192 + row * 32 + sg * 8]), 16, 0, 0);
    }
  };

  stage(0);
  stage(1);
  asm volatile("s_waitcnt vmcnt(4)" ::: "memory");   // tile 0 landed (mine)
  asm volatile("s_barrier" ::: "memory");            // tile 0 landed (all waves)

  for (int t = 0; t < nt; ++t) {
    if (t + 2 < nt) {
      stage(t + 2);
      asm volatile("s_waitcnt vmcnt(4)" ::: "memory");   // tile t+1 landed; t+2 in flight
    } else {
      asm volatile("s_waitcnt vmcnt(0)" ::: "memory");   // tail drain
    }
    asm volatile("s_barrier" ::: "memory");              // globalize tile t+1 / protect ring
    const int slot = t % 3;
    const _Float16* as = &Asl[slot * 8192];
    const _Float16* bs = &Bsl[slot * 8192];
    h16x8 af[8], bf[4];
#pragma unroll
    for (int mi = 0; mi < 8; ++mi)
      af[mi] = *(const h16x8*)&as[(wm * 128 + mi * 16 + fr) * 32 + fc * 8];
#pragma unroll
    for (int ni = 0; ni < 4; ++ni)
      bf[ni] = *(const h16x8*)&bs[(wn * 64 + ni * 16 + fr) * 32 + fc * 8];
    __builtin_amdgcn_s_setprio(1);
#pragma unroll
    for (int mi = 0; mi < 8; ++mi)
#pragma unroll
      for (int ni = 0; ni < 4; ++ni)
        acc[mi][ni] = __builtin_amdgcn_mfma_f32_16x16x32_f16(af[mi], bf[ni], acc[mi][ni], 0, 0, 0);
    __builtin_amdgcn_s_setprio(0);
    asm volatile("s_barrier" ::: "memory");   // my reads of slot done before others restage it
  }

  const int rbase = tm * 256 + wm * 128;
  const int cbase = tn * 256 + wn * 64;
#pragma unroll
  for (int mi = 0; mi < 8; ++mi) {
#pragma unroll
    for (int ni = 0; ni < 4; ++ni) {
#pragma unroll
      for (int r = 0; r < 4; ++r) {
        int mm = rbase + mi * 16 + fc * 4 + r;
        int nn = cbase + ni * 16 + fr;
        float v = acc[mi][ni][r];
        if (EPI == 0) {
          ((float*)C)[(size_t)mm * N + nn] = v + bias1[nn];
        } else {
          ((_Float16*)C)[(size_t)mm * N + nn] = (_Float16)(v + bias1[nn] + bias2[nn]);
        }
      }
    }
  }
}

// ---------------- persistent pipelined LSTM recurrence (R11-proven, unchanged) ----------------
__global__ __launch_bounds__(512) void k_recur(const _Float16* __restrict__ Wp4,
                                               const _Float16* __restrict__ Wp0,
                                               const _Float16* __restrict__ X0bf,
                                               _Float16* __restrict__ hfrag0,
                                               _Float16* __restrict__ hfragH,
                                               _Float16* __restrict__ h2all,
                                               _Float16* __restrict__ concat,
                                               const float* __restrict__ bih,
                                               const float* __restrict__ bhh,
                                               const float* __restrict__ c0p,
                                               unsigned* __restrict__ sync) {
  extern __shared__ char lds[];
  _Float16* ldsW = (_Float16*)lds;                 // 65536 f16
  float* redbuf = (float*)(lds + 131072);          // [3][3][2][256]
  _Float16* hstage = (_Float16*)(lds + 131072);    // [3][128] (reused after redbuf)
  float* gbuf = (float*)(lds + 149504);            // [3][32][16]
  unsigned* arrive = sync + 64;                    // strided: arrive[w*32]

  const int w = blockIdx.x;
  const int wp = (w & 7) * 32 + (w >> 3);          // XCD-local unit-block remap
  const int tid = threadIdx.x, lane = tid & 63, wv = tid >> 6;
  const int tb = wv & 1, kq = wv >> 1;
  const int row = (lane >> 4) * 4, col = lane & 15;

  for (int i = 0; i < 16; ++i) {
    int eo = (i * 512 + tid) * 8;
    *(h16x8*)&ldsW[eo] = *(const h16x8*)(Wp4 + (size_t)w * 65536 + eo);
  }
  h16x8 w0reg[8];
#pragma unroll
  for (int i = 0; i < 8; ++i)
    w0reg[i] = *(const h16x8*)(Wp0 + (size_t)w * 16384 + ((size_t)(kq * 8 + i) * 64 + lane) * 8);

  const int eb = tid >> 2, eni = tid & 3, en = wp * 4 + eni;
  float c0r = 0.f, c1r = 0.f, c2r = 0.f;
  float b1r[4] = {0, 0, 0, 0}, b2r[4] = {0, 0, 0, 0};
  if (tid < 128) {
    c0r = c0p[0 * BB * HH + eb * HH + en];
    c1r = c0p[1 * BB * HH + eb * HH + en];
    c2r = c0p[2 * BB * HH + eb * HH + en];
#pragma unroll
    for (int g = 0; g < 4; ++g) {
      b1r[g] = bih[1 * G4 + g * 1024 + en] + bhh[1 * G4 + g * 1024 + en];
      b2r[g] = bih[2 * G4 + g * 1024 + en] + bhh[2 * G4 + g * 1024 + en];
    }
  }
  const int pk_l = tid >> 5, pk_r = tid & 31;
  const size_t pk_idx = ((size_t)(((pk_r >> 4) * 32 + (wp >> 3)) * 64 + (pk_r & 15) +
                                  (((wp >> 1) & 3) << 4))) * 8 + 4 * (wp & 1);
  __syncthreads();

  for (int tau = 0; tau < 130; ++tau) {
    const _Float16* rb = (tau < 3) ? (hfrag0 + (size_t)tau * 98304)
                                   : (hfragH + (size_t)(tau - 3) * 98304);
    _Float16* wb = (tau + 1 < 3) ? (hfrag0 + (size_t)(tau + 1) * 98304)
                                 : (hfragH + (size_t)(tau - 2) * 98304);
    const _Float16* h0r = rb;
    const _Float16* h1r = rb + 32768;
    const _Float16* h2r = rb + 65536;

    h16x8 a0[8], a1[8], a2[8];
#pragma unroll
    for (int i = 0; i < 8; ++i) {
      int ks = kq * 8 + i;
      size_t off = ((size_t)(tb * 32 + ks) * 64 + lane) * 8;
      a0[i] = *(const h16x8*)(h0r + off);
      a1[i] = *(const h16x8*)(h1r + off);
      a2[i] = *(const h16x8*)(h2r + off);
    }
    float xg0 = 0.f, xg1 = 0.f, xg2 = 0.f, xg3 = 0.f;
    if (tid < 128 && tau < 128) {
      size_t xb = ((size_t)(tau * BB + eb)) * G4 + en;
      xg0 = (float)X0bf[xb];        xg1 = (float)X0bf[xb + 1024];
      xg2 = (float)X0bf[xb + 2048]; xg3 = (float)X0bf[xb + 3072];
    }
    f32x4 acc0 = {}, acc1 = {}, acc2 = {};
#pragma unroll
    for (int i = 0; i < 8; ++i) {
      int ks = kq * 8 + i;
      int jj = lane & 15, q = lane >> 4;
      int kk = (ks * 32 + q * 8) ^ ((jj & 7) << 3);
      const h16x8 bw1i = *(const h16x8*)&ldsW[0 * 16384 + jj * 1024 + kk];
      const h16x8 bw1h = *(const h16x8*)&ldsW[1 * 16384 + jj * 1024 + kk];
      const h16x8 bw2i = *(const h16x8*)&ldsW[2 * 16384 + jj * 1024 + kk];
      const h16x8 bw2h = *(const h16x8*)&ldsW[3 * 16384 + jj * 1024 + kk];
      acc0 = __builtin_amdgcn_mfma_f32_16x16x32_f16(a0[i], w0reg[i], acc0, 0, 0, 0);
      acc1 = __builtin_amdgcn_mfma_f32_16x16x32_f16(a0[i], bw1i, acc1, 0, 0, 0);
      acc1 = __builtin_amdgcn_mfma_f32_16x16x32_f16(a1[i], bw1h, acc1, 0, 0, 0);
      acc2 = __builtin_amdgcn_mfma_f32_16x16x32_f16(a1[i], bw2i, acc2, 0, 0, 0);
      acc2 = __builtin_amdgcn_mfma_f32_16x16x32_f16(a2[i], bw2h, acc2, 0, 0, 0);
    }
    if (kq >= 1) {
      int s = kq - 1;
#pragma unroll
      for (int r = 0; r < 4; ++r) {
        redbuf[((0 * 3 + s) * 2 + tb) * 256 + (row + r) * 16 + col] = acc0[r];
        redbuf[((1 * 3 + s) * 2 + tb) * 256 + (row + r) * 16 + col] = acc1[r];
        redbuf[((2 * 3 + s) * 2 + tb) * 256 + (row + r) * 16 + col] = acc2[r];
      }
    }
    __syncthreads();
    if (kq == 0) {
#pragma unroll
      for (int r = 0; r < 4; ++r) {
        float v0 = acc0[r], v1 = acc1[r], v2 = acc2[r];
#pragma unroll
        for (int s = 0; s < 3; ++s) {
          v0 += redbuf[((0 * 3 + s) * 2 + tb) * 256 + (row + r) * 16 + col];
          v1 += redbuf[((1 * 3 + s) * 2 + tb) * 256 + (row + r) * 16 + col];
          v2 += redbuf[((2 * 3 + s) * 2 + tb) * 256 + (row + r) * 16 + col];
        }
        gbuf[(0 * 32 + tb * 16 + row + r) * 16 + col] = v0;
        gbuf[(1 * 32 + tb * 16 + row + r) * 16 + col] = v1;
        gbuf[(2 * 32 + tb * 16 + row + r) * 16 + col] = v2;
      }
    }
    __syncthreads();
    if (tid < 128) {
      if (tau < 128) {
        float gi = gbuf[(0 * 32 + eb) * 16 + eni] + xg0;
        float gf = gbuf[(0 * 32 + eb) * 16 + 4 + eni] + xg1;
        float gg = gbuf[(0 * 32 + eb) * 16 + 8 + eni] + xg2;
        float go = gbuf[(0 * 32 + eb) * 16 + 12 + eni] + xg3;
        c0r = sigmf(gf) * c0r + sigmf(gi) * tanhf(gg);
        hstage[0 * 128 + tid] = (_Float16)(sigmf(go) * tanhf(c0r));
      }
      if (tau >= 1 && tau < 129) {
        float gi = gbuf[(1 * 32 + eb) * 16 + eni] + b1r[0];
        float gf = gbuf[(1 * 32 + eb) * 16 + 4 + eni] + b1r[1];
        float gg = gbuf[(1 * 32 + eb) * 16 + 8 + eni] + b1r[2];
        float go = gbuf[(1 * 32 + eb) * 16 + 12 + eni] + b1r[3];
        c1r = sigmf(gf) * c1r + sigmf(gi) * tanhf(gg);
        hstage[1 * 128 + tid] = (_Float16)(sigmf(go) * tanhf(c1r));
      }
      if (tau >= 2) {
        float gi = gbuf[(2 * 32 + eb) * 16 + eni] + b2r[0];
        float gf = gbuf[(2 * 32 + eb) * 16 + 4 + eni] + b2r[1];
        float gg = gbuf[(2 * 32 + eb) * 16 + 8 + eni] + b2r[2];
        float go = gbuf[(2 * 32 + eb) * 16 + 12 + eni] + b2r[3];
        c2r = sigmf(gf) * c2r + sigmf(gi) * tanhf(gg);
        float h = sigmf(go) * tanhf(c2r);
        _Float16 hb = (_Float16)h;
        hstage[2 * 128 + tid] = hb;
        int t2 = tau - 2;
        h2all[(size_t)(t2 * BB + eb) * HH + en] = hb;
        concat[(size_t)(t2 * BB + eb) * 2048 + 1024 + en] = hb;
      }
    }
    __syncthreads();
    {
      bool act = (tid < 96) &&
                 ((pk_l == 0) ? (tau < 128)
                  : (pk_l == 1) ? (tau >= 1 && tau < 129)
                                : (tau >= 2 && tau < 129));
      if (act) {
        unsigned long long v = *(const unsigned long long*)&hstage[pk_l * 128 + pk_r * 4];
        __hip_atomic_store(
            (unsigned long long*)(wb + (size_t)pk_l * 32768 + pk_idx), v,
            __ATOMIC_RELAXED, __HIP_MEMORY_SCOPE_AGENT);
      }
      asm volatile("s_waitcnt vmcnt(0)" ::: "memory");
    }
    __syncthreads();
    if (tid == 0)
      __hip_atomic_store(&arrive[w * 32], (unsigned)(tau + 1), __ATOMIC_RELAXED,
                         __HIP_MEMORY_SCOPE_AGENT);
    if (tau < 129) {
      if (tid < 64) {
        for (;;) {
          bool ok = true;
#pragma unroll
          for (int j = 0; j < 4; ++j) {
            unsigned v = __hip_atomic_load(&arrive[(tid * 4 + j) * 32], __ATOMIC_RELAXED,
                                           __HIP_MEMORY_SCOPE_AGENT);
            ok &= (v >= (unsigned)(tau + 1));
          }
          if (__all(ok)) break;
          __builtin_amdgcn_s_sleep(1);
        }
        asm volatile("" ::: "memory");
      }
      __syncthreads();
    }
  }
}

// ---------------- fused scores+softmax+weighted-context per (t,b) (R11-proven) ----------------
__global__ __launch_bounds__(256) void k_attn(const _Float16* __restrict__ target,
                                              const _Float16* __restrict__ encb,
                                              _Float16* __restrict__ concat) {
  __shared__ float sc[64];
  __shared__ float att[64];
  int m = blockIdx.x, b = m & 31;
  int tid = threadIdx.x, lane = tid & 63, wv = tid >> 6;
  const h16x8* tp = (const h16x8*)(target + (size_t)m * EE + lane * 16);
  h16x8 tg0 = tp[0], tg1 = tp[1];
  for (int si = 0; si < 16; ++si) {
    int s = wv * 16 + si;
    const h16x8* ep = (const h16x8*)(encb + ((size_t)s * BB + b) * EE + lane * 16);
    h16x8 e0 = ep[0], e1 = ep[1];
    float a = 0.f;
#pragma unroll
    for (int j = 0; j < 8; ++j) a += (float)e0[j] * (float)tg0[j];
#pragma unroll
    for (int j = 0; j < 8; ++j) a += (float)e1[j] * (float)tg1[j];
#pragma unroll
    for (int off = 32; off >= 1; off >>= 1) a += __shfl_xor(a, off);
    if (lane == 0) sc[s] = a;
  }
  __syncthreads();
  if (wv == 0) {
    float v = sc[lane], mx = v;
#pragma unroll
    for (int off = 32; off >= 1; off >>= 1) mx = fmaxf(mx, __shfl_xor(mx, off));
    float e = expf(v - mx), sm = e;
#pragma unroll
    for (int off = 32; off >= 1; off >>= 1) sm += __shfl_xor(sm, off);
    att[lane] = e / sm;
  }
  __syncthreads();
  int e4 = tid * 4;
  float a0 = 0, a1 = 0, a2 = 0, a3 = 0;
  for (int s = 0; s < 64; ++s) {
    float wgt = att[s];
    h16x4 ev = *(const h16x4*)(encb + ((size_t)s * BB + b) * EE + e4);
    a0 += wgt * (float)ev[0]; a1 += wgt * (float)ev[1];
    a2 += wgt * (float)ev[2]; a3 += wgt * (float)ev[3];
  }
  h16x4 o; o[0] = (_Float16)a0; o[1] = (_Float16)a1; o[2] = (_Float16)a2; o[3] = (_Float16)a3;
  *(h16x4*)(concat + (size_t)m * 2048 + e4) = o;
}

// ---------------- host ----------------
extern "C" void kernel_launch(void* const* d_in, const int* in_sizes, int n_in,
                              void* d_out, int out_size, void* d_ws, size_t ws_size,
                              hipStream_t stream) {
  const int* tokens = (const int*)d_in[0];
  const float* embW = (const float*)d_in[1];
  const float* Wih = (const float*)d_in[2];
  const float* Whh = (const float*)d_in[3];
  const float* bih = (const float*)d_in[4];
  const float* bhh = (const float*)d_in[5];
  const float* Win = (const float*)d_in[6];
  const float* Wout = (const float*)d_in[7];
  const float* finalb = (const float*)d_in[8];
  const float* enc = (const float*)d_in[9];
  const float* h0 = (const float*)d_in[10];
  const float* c0 = (const float*)d_in[11];
  (void)in_sizes; (void)n_in; (void)out_size;
  if (ws_size < WS_NEEDED) return;

  char* ws = (char*)d_ws;
  unsigned* sync = (unsigned*)(ws + OFF_SYNC);
  _Float16* hfrag0 = (_Float16*)(ws + OFF_HFRAG0);
  _Float16* hfragH = (_Float16*)(ws + OFF_HFRAGH);
  _Float16* emb = (_Float16*)(ws + OFF_EMB);
  _Float16* X0bf = (_Float16*)(ws + OFF_X0);
  _Float16* Wih0b = (_Float16*)(ws + OFF_WIH0);
  _Float16* Wp4 = (_Float16*)(ws + OFF_WP4);
  _Float16* Wp0 = (_Float16*)(ws + OFF_WP0);
  _Float16* embWb = (_Float16*)(ws + OFF_EMBW);
  _Float16* Winb = (_Float16*)(ws + OFF_WIN);
  _Float16* Woutb = (_Float16*)(ws + OFF_WOUT);
  _Float16* encb = (_Float16*)(ws + OFF_ENC);
  _Float16* h2all = (_Float16*)(ws + OFF_H2ALL);
  _Float16* concat = (_Float16*)(ws + OFF_CONCAT);
  _Float16* target = (_Float16*)(ws + OFF_TARGET);
  _Float16* ht = (_Float16*)(ws + OFF_HT);

  const unsigned LDSB = 155648;   // k_recur
  const unsigned LDSG = 98304;    // k_gemm256: 3 slots x (A 16KB + B 16KB)
  static int lds_set = 0;
  if (!lds_set) {
    hipFuncSetAttribute((const void*)k_recur, hipFuncAttributeMaxDynamicSharedMemorySize,
                        (int)LDSB);
    hipFuncSetAttribute((const void*)k_gemm256<0>, hipFuncAttributeMaxDynamicSharedMemorySize,
                        (int)LDSG);
    hipFuncSetAttribute((const void*)k_gemm256<1>, hipFuncAttributeMaxDynamicSharedMemorySize,
                        (int)LDSG);
    lds_set = 1;
  }

  // prep: one merged convert + gather + packs + init
  k_convall<<<4096, 256, 0, stream>>>(embW, embWb, VV * EE / 4,
                                      Wih, Wih0b, G4 * EE / 4,
                                      Win, Winb, EE * EE / 4,
                                      Wout, Woutb, EE * 2048 / 4,
                                      enc, encb, 64 * BB * EE / 4);
  k_gather<<<NROWS, 256, 0, stream>>>(tokens, embWb, emb);
  k_packw4<<<8192, 256, 0, stream>>>(Wih, Whh, Wp4);
  k_packw0<<<4096, 256, 0, stream>>>(Whh, Wp0);
  k_init<<<384, 256, 0, stream>>>(h0, hfrag0, sync);

  // X0 = emb @ Wih0^T + b_ih0 + b_hh0   -> f16 [4096,4096]
  k_gemm256<1><<<16 * 16, 512, LDSG, stream>>>(emb, Wih0b, X0bf, NROWS, G4, EE, bih, bhh);

  // recurrence: REGULAR launch (graph-capturable); co-residency structural
  k_recur<<<256, 512, LDSB, stream>>>(Wp4, Wp0, X0bf, hfrag0, hfragH, h2all, concat,
                                      bih, bhh, c0, sync);

  // attention chain
  k_gemm<1><<<32 * 8, 256, 0, stream>>>(h2all, Winb, target, NROWS, EE, EE, nullptr, nullptr);
  k_attn<<<NROWS, 256, 0, stream>>>(target, encb, concat);
  k_gemm<2><<<32 * 8, 256, 0, stream>>>(concat, Woutb, ht, NROWS, EE, 2048, nullptr, nullptr);

  // logits = ht @ embW^T + final_b  -> f32 d_out
  k_gemm256<0><<<16 * 125, 512, LDSG, stream>>>(ht, embWb, d_out, NROWS, VV, EE, finalb, nullptr);
}

// Round 15
// 1408.076 us; speedup vs baseline: 1.0818x; 1.0035x over previous
//
#include <hip/hip_runtime.h>
#include <cstdint>
#include <cstddef>

#define SEQ   128
#define BB    32
#define EE    1024
#define HH    1024
#define G4    4096
#define VV    32000
#define NROWS 4096   // SEQ*BB

typedef _Float16 h16x8 __attribute__((ext_vector_type(8)));
typedef _Float16 h16x4 __attribute__((ext_vector_type(4)));
typedef float f32x4  __attribute__((ext_vector_type(4)));

#define AS_G(p) ((const __attribute__((address_space(1))) void*)(p))
#define AS_L(p) ((__attribute__((address_space(3))) void*)(p))

__device__ __forceinline__ float sigmf(float x) { return 1.0f / (1.0f + expf(-x)); }

// ---------------- ws layout (bytes) ----------------
// hfrag = monotonic slot ring: slot s holds [3 layers][32768 f16] (196608 B).
// slots 0..2: dedicated region; slots 3..129 overlay EMB+WIH0+TARGET (dead
// during the recurrence).
#define OFF_SYNC    0ull                      // pad[64] + arrive[256] strided 128B
#define OFF_HFRAG0  40960ull                  // 3 slots  * 196608 = 589824
#define OFF_EMB     630784ull                 // [4096][1024] f16   (8388608)
#define OFF_WIH0    9019392ull                // [4096][1024] f16   (8388608)
#define OFF_TARGET  17408000ull               // [4096][1024] f16   (8388608)
#define OFF_HT      25796608ull               // [4096][1024] f16   (8388608)
#define OFF_HFRAGH  630784ull                 // 127 slots * 196608 (overlay)
#define OFF_X0      34185216ull               // [4096][4096] f16   (33554432)
#define OFF_WP4     67739648ull               // 256 wg * 65536 f16 (33554432)
#define OFF_WP0     101294080ull              // 256 wg * 16384 f16 (8388608)
#define OFF_EMBW    109682688ull              // [32000][1024] f16  (65536000)
#define OFF_WIN     175218688ull              // [1024][1024] f16   (2097152)
#define OFF_WOUT    177315840ull              // [1024][2048] f16   (4194304)
#define OFF_ENC     181510144ull              // [64][32][1024] f16 (4194304)
#define OFF_H2ALL   185704448ull              // [4096][1024] f16   (8388608)
#define OFF_CONCAT  194093056ull              // [4096][2048] f16   (16777216)
#define WS_NEEDED   210870272ull

// ---------------- merged f32 -> f16 convert: 5 segments in ONE launch ----------------
__global__ __launch_bounds__(256) void k_convall(const float* __restrict__ s0, _Float16* d0, int n0,
                                                 const float* __restrict__ s1, _Float16* d1, int n1,
                                                 const float* __restrict__ s2, _Float16* d2, int n2,
                                                 const float* __restrict__ s3, _Float16* d3, int n3,
                                                 const float* __restrict__ s4, _Float16* d4, int n4) {
  const int base = blockIdx.x * blockDim.x + threadIdx.x;
  const int st = gridDim.x * blockDim.x;
#pragma unroll 1
  for (int seg = 0; seg < 5; ++seg) {
    const float* s = seg == 0 ? s0 : seg == 1 ? s1 : seg == 2 ? s2 : seg == 3 ? s3 : s4;
    _Float16* d = seg == 0 ? d0 : seg == 1 ? d1 : seg == 2 ? d2 : seg == 3 ? d3 : d4;
    int n = seg == 0 ? n0 : seg == 1 ? n1 : seg == 2 ? n2 : seg == 3 ? n3 : n4;
    for (int i = base; i < n; i += st) {
      float4 v = ((const float4*)s)[i];
      h16x4 o; o[0] = (_Float16)v.x; o[1] = (_Float16)v.y; o[2] = (_Float16)v.z; o[3] = (_Float16)v.w;
      ((h16x4*)d)[i] = o;
    }
  }
}

// ---------------- embedding gather from f16 table ----------------
__global__ __launch_bounds__(256) void k_gather(const int* __restrict__ tok,
                                                const _Float16* __restrict__ embWb,
                                                _Float16* __restrict__ emb) {
  int row = blockIdx.x;                 // row = t*32+b
  int t = tok[row];
  h16x4 v = ((const h16x4*)(embWb + (size_t)t * EE))[threadIdx.x];
  ((h16x4*)(emb + (size_t)row * EE))[threadIdx.x] = v;
}

// ---------------- pack 4 LDS-resident matrices (Wih1,Whh1,Wih2,Whh2) ----------------
// wg w owns hidden units 4*wp..4*wp+3 with wp=(w&7)*32+(w>>3)  (XCD-local X0 lines)
__global__ __launch_bounds__(256) void k_packw4(const float* __restrict__ Wih,
                                                const float* __restrict__ Whh,
                                                _Float16* __restrict__ out) {
  int i = blockIdx.x * blockDim.x + threadIdx.x;
  int st = gridDim.x * blockDim.x;
  const int total = 256 * 65536;
  for (; i < total; i += st) {
    int w = i >> 16, rem = i & 65535;
    int wp = (w & 7) * 32 + (w >> 3);
    int mat = rem >> 14, jj = (rem >> 10) & 15, k = rem & 1023;
    int layer = 1 + (mat >> 1), isHH = mat & 1;
    int row = ((jj >> 2) << 10) + (wp << 2) + (jj & 3);
    int ks = k ^ ((jj & 7) << 3);
    const float* src = (isHH ? Whh : Wih) + (size_t)layer * G4 * 1024 + (size_t)row * 1024 + ks;
    out[i] = (_Float16)(*src);
  }
}

// ---------------- pack Whh0 fragment-linear: [w][ks 0..31][lane 0..63][e 0..7] ----------------
__global__ __launch_bounds__(256) void k_packw0(const float* __restrict__ Whh,
                                                _Float16* __restrict__ out) {
  int i = blockIdx.x * blockDim.x + threadIdx.x;
  int st = gridDim.x * blockDim.x;
  const int total = 256 * 16384;
  for (; i < total; i += st) {
    int w = i >> 14, rem = i & 16383;
    int wp = (w & 7) * 32 + (w >> 3);
    int ks = rem >> 9, lane = (rem >> 3) & 63, e = rem & 7;
    int jj = lane & 15, q = lane >> 4;
    int row = ((jj >> 2) << 10) + (wp << 2) + (jj & 3);
    int k = ks * 32 + q * 8 + e;
    out[i] = (_Float16)Whh[(size_t)row * 1024 + k];   // layer 0
  }
}

// ---------------- init: sync flags + initial h into slots 0..2 ----------------
__global__ __launch_bounds__(256) void k_init(const float* __restrict__ h0,
                                              _Float16* __restrict__ hfrag0,
                                              unsigned* __restrict__ sync) {
  int i = blockIdx.x * blockDim.x + threadIdx.x;
  if (i < 64 + 8192) sync[i] = 0u;   // pad + arrive (strided)
  if (i >= 3 * BB * HH) return;
  int l = i >> 15, rem = i & 32767;
  int b = rem >> 10, n = rem & 1023;
  int tbb = b >> 4, ks = n >> 5, q = (n >> 3) & 3, e = n & 7;
  int lane2 = (b & 15) | (q << 4);
  hfrag0[(size_t)l * 131072 + ((size_t)(tbb * 32 + ks) * 64 + lane2) * 8 + e] =
      (_Float16)h0[i];
}

// ---------------- generic 128x128 BT GEMM (A[M,K] f16, B[N,K] f16) ----------------
// EPI: 1 = f16 ; 2 = f16(tanh)   (big GEMMs use k_gemm256)
template <int EPI>
__global__ __launch_bounds__(256) void k_gemm(const _Float16* __restrict__ A,
                                              const _Float16* __restrict__ B,
                                              void* __restrict__ C, int M, int N, int K,
                                              const float* __restrict__ bias1,
                                              const float* __restrict__ bias2) {
  __shared__ _Float16 As[2][128 * 32];
  __shared__ _Float16 Bs[2][128 * 32];
  const int ntn = N / 128;
  const int nwg = gridDim.x;
  const int bid = (blockIdx.x & 7) * (nwg >> 3) + (blockIdx.x >> 3);
  const int tm = bid / ntn, tn = bid % ntn;
  const int tid = threadIdx.x, lane = tid & 63;
  const int wv = tid >> 6, wr = wv >> 1, wc = wv & 1;
  f32x4 acc[4][4] = {};

  auto stage = [&](int buf, int k0) {
#pragma unroll
    for (int i = 0; i < 2; ++i) {
      int eo = (i * 256 + tid) * 8;
      int r = eo >> 5, c = eo & 31;
      __builtin_amdgcn_global_load_lds(AS_G(A + (size_t)(tm * 128 + r) * K + k0 + c),
                                       AS_L(&As[buf][eo]), 16, 0, 0);
      __builtin_amdgcn_global_load_lds(AS_G(B + (size_t)(tn * 128 + r) * K + k0 + c),
                                       AS_L(&Bs[buf][eo]), 16, 0, 0);
    }
  };
  stage(0, 0);
  __syncthreads();
  const int nk = K / 32;
  for (int kt = 0; kt < nk; ++kt) {
    if (kt + 1 < nk) stage((kt + 1) & 1, (kt + 1) * 32);
    const int buf = kt & 1;
    h16x8 af[4], bfr[4];
#pragma unroll
    for (int mi = 0; mi < 4; ++mi)
      af[mi] = *(const h16x8*)&As[buf][(wr * 64 + mi * 16 + (lane & 15)) * 32 + (lane >> 4) * 8];
#pragma unroll
    for (int ni = 0; ni < 4; ++ni)
      bfr[ni] = *(const h16x8*)&Bs[buf][(wc * 64 + ni * 16 + (lane & 15)) * 32 + (lane >> 4) * 8];
#pragma unroll
    for (int mi = 0; mi < 4; ++mi)
#pragma unroll
      for (int ni = 0; ni < 4; ++ni)
        acc[mi][ni] = __builtin_amdgcn_mfma_f32_16x16x32_f16(af[mi], bfr[ni], acc[mi][ni], 0, 0, 0);
    __syncthreads();
  }
  const int rbase = tm * 128 + wr * 64;
  const int cbase = tn * 128 + wc * 64;
#pragma unroll
  for (int mi = 0; mi < 4; ++mi) {
#pragma unroll
    for (int ni = 0; ni < 4; ++ni) {
#pragma unroll
      for (int r = 0; r < 4; ++r) {
        int mm = rbase + mi * 16 + (lane >> 4) * 4 + r;
        int nn = cbase + ni * 16 + (lane & 15);
        float v = acc[mi][ni][r];
        if (EPI == 1) {
          ((_Float16*)C)[(size_t)mm * N + nn] = (_Float16)v;
        } else {
          ((_Float16*)C)[(size_t)mm * N + nn] = (_Float16)tanhf(v);
        }
      }
    }
  }
}

// ---------------- 256x256 BT GEMM, 3-slot LDS ring + counted vmcnt (T4) ----------------
// R11-proven: 512 thr, 8 waves, depth-2 prefetch, vmcnt(4), tm-MAJOR mapping.
// EPI: 0 = f32 + bias1 ; 1 = f16 + bias1 + bias2
template <int EPI>
__global__ __launch_bounds__(512, 2) void k_gemm256(const _Float16* __restrict__ A,
                                                    const _Float16* __restrict__ B,
                                                    void* __restrict__ C, int M, int N, int K,
                                                    const float* __restrict__ bias1,
                                                    const float* __restrict__ bias2) {
  extern __shared__ char glds[];
  _Float16* Asl = (_Float16*)glds;                     // [3][256*32]
  _Float16* Bsl = (_Float16*)(glds + 3 * 8192 * 2);    // [3][256*32]
  const int ntn = N / 256;
  const int nwg = gridDim.x;
  const int bid = (blockIdx.x & 7) * (nwg >> 3) + (blockIdx.x >> 3);
  const int tm = bid / ntn, tn = bid % ntn;            // tm-major (R11)
  const int tid = threadIdx.x, lane = tid & 63;
  const int wid = tid >> 6, wm = wid >> 2, wn = wid & 3;
  const int fr = lane & 15, fc = lane >> 4;
  const int srow0 = tid >> 2, sg = tid & 3;    // staging: row within 128-half, granule

  f32x4 acc[8][4] = {};
  const int nt = K / 32;

  auto stage = [&](int t) {
    const int slot = t % 3;
    const size_t kof = (size_t)t * 32 + sg * 8;
#pragma unroll
    for (int r = 0; r < 2; ++r) {
      int row = r * 128 + srow0;
      __builtin_amdgcn_global_load_lds(AS_G(A + (size_t)(tm * 256 + row) * K + kof),
                                       AS_L(&Asl[slot * 8192 + row * 32 + sg * 8]), 16, 0, 0);
    }
#pragma unroll
    for (int r = 0; r < 2; ++r) {
      int row = r * 128 + srow0;
      __builtin_amdgcn_global_load_lds(AS_G(B + (size_t)(tn * 256 + row) * K + kof),
                                       AS_L(&Bsl[slot * 8192 + row * 32 + sg * 8]), 16, 0, 0);
    }
  };

  stage(0);
  stage(1);
  asm volatile("s_waitcnt vmcnt(4)" ::: "memory");   // tile 0 landed (mine)
  asm volatile("s_barrier" ::: "memory");            // tile 0 landed (all waves)

  for (int t = 0; t < nt; ++t) {
    if (t + 2 < nt) {
      stage(t + 2);
      asm volatile("s_waitcnt vmcnt(4)" ::: "memory");   // tile t+1 landed; t+2 in flight
    } else {
      asm volatile("s_waitcnt vmcnt(0)" ::: "memory");   // tail drain
    }
    asm volatile("s_barrier" ::: "memory");              // globalize tile t+1 / protect ring
    const int slot = t % 3;
    const _Float16* as = &Asl[slot * 8192];
    const _Float16* bs = &Bsl[slot * 8192];
    h16x8 af[8], bf[4];
#pragma unroll
    for (int mi = 0; mi < 8; ++mi)
      af[mi] = *(const h16x8*)&as[(wm * 128 + mi * 16 + fr) * 32 + fc * 8];
#pragma unroll
    for (int ni = 0; ni < 4; ++ni)
      bf[ni] = *(const h16x8*)&bs[(wn * 64 + ni * 16 + fr) * 32 + fc * 8];
    __builtin_amdgcn_s_setprio(1);
#pragma unroll
    for (int mi = 0; mi < 8; ++mi)
#pragma unroll
      for (int ni = 0; ni < 4; ++ni)
        acc[mi][ni] = __builtin_amdgcn_mfma_f32_16x16x32_f16(af[mi], bf[ni], acc[mi][ni], 0, 0, 0);
    __builtin_amdgcn_s_setprio(0);
    asm volatile("s_barrier" ::: "memory");   // my reads of slot done before others restage it
  }

  const int rbase = tm * 256 + wm * 128;
  const int cbase = tn * 256 + wn * 64;
#pragma unroll
  for (int mi = 0; mi < 8; ++mi) {
#pragma unroll
    for (int ni = 0; ni < 4; ++ni) {
#pragma unroll
      for (int r = 0; r < 4; ++r) {
        int mm = rbase + mi * 16 + fc * 4 + r;
        int nn = cbase + ni * 16 + fr;
        float v = acc[mi][ni][r];
        if (EPI == 0) {
          ((float*)C)[(size_t)mm * N + nn] = v + bias1[nn];
        } else {
          ((_Float16*)C)[(size_t)mm * N + nn] = (_Float16)(v + bias1[nn] + bias2[nn]);
        }
      }
    }
  }
}

// ---------------- persistent pipelined LSTM recurrence ----------------
// R14 + deferred-output-store fix: h2all/concat HBM stores moved AFTER the
// pack vmcnt(0) + flag (they were draining inside the pre-flag vmcnt(0),
// putting an HBM write-ack on the per-tick critical path; they are consumed
// only by post-recurrence kernels, so ordering vs the flag is irrelevant).
__global__ __launch_bounds__(512) void k_recur(const _Float16* __restrict__ Wp4,
                                               const _Float16* __restrict__ Wp0,
                                               const _Float16* __restrict__ X0bf,
                                               _Float16* __restrict__ hfrag0,
                                               _Float16* __restrict__ hfragH,
                                               _Float16* __restrict__ h2all,
                                               _Float16* __restrict__ concat,
                                               const float* __restrict__ bih,
                                               const float* __restrict__ bhh,
                                               const float* __restrict__ c0p,
                                               unsigned* __restrict__ sync) {
  extern __shared__ char lds[];
  _Float16* ldsW = (_Float16*)lds;                 // 65536 f16
  float* redbuf = (float*)(lds + 131072);          // [3][3][2][256]
  _Float16* hstage = (_Float16*)(lds + 131072);    // [3][128] (reused after redbuf)
  float* gbuf = (float*)(lds + 149504);            // [3][32][16]
  unsigned* arrive = sync + 64;                    // strided: arrive[w*32]

  const int w = blockIdx.x;
  const int wp = (w & 7) * 32 + (w >> 3);          // XCD-local unit-block remap
  const int tid = threadIdx.x, lane = tid & 63, wv = tid >> 6;
  const int tb = wv & 1, kq = wv >> 1;
  const int row = (lane >> 4) * 4, col = lane & 15;

  for (int i = 0; i < 16; ++i) {
    int eo = (i * 512 + tid) * 8;
    *(h16x8*)&ldsW[eo] = *(const h16x8*)(Wp4 + (size_t)w * 65536 + eo);
  }
  h16x8 w0reg[8];
#pragma unroll
  for (int i = 0; i < 8; ++i)
    w0reg[i] = *(const h16x8*)(Wp0 + (size_t)w * 16384 + ((size_t)(kq * 8 + i) * 64 + lane) * 8);

  const int eb = tid >> 2, eni = tid & 3, en = wp * 4 + eni;
  float c0r = 0.f, c1r = 0.f, c2r = 0.f;
  float b1r[4] = {0, 0, 0, 0}, b2r[4] = {0, 0, 0, 0};
  if (tid < 128) {
    c0r = c0p[0 * BB * HH + eb * HH + en];
    c1r = c0p[1 * BB * HH + eb * HH + en];
    c2r = c0p[2 * BB * HH + eb * HH + en];
#pragma unroll
    for (int g = 0; g < 4; ++g) {
      b1r[g] = bih[1 * G4 + g * 1024 + en] + bhh[1 * G4 + g * 1024 + en];
      b2r[g] = bih[2 * G4 + g * 1024 + en] + bhh[2 * G4 + g * 1024 + en];
    }
  }
  const int pk_l = tid >> 5, pk_r = tid & 31;
  const size_t pk_idx = ((size_t)(((pk_r >> 4) * 32 + (wp >> 3)) * 64 + (pk_r & 15) +
                                  (((wp >> 1) & 3) << 4))) * 8 + 4 * (wp & 1);
  __syncthreads();

  for (int tau = 0; tau < 130; ++tau) {
    const _Float16* rb = (tau < 3) ? (hfrag0 + (size_t)tau * 98304)
                                   : (hfragH + (size_t)(tau - 3) * 98304);
    _Float16* wb = (tau + 1 < 3) ? (hfrag0 + (size_t)(tau + 1) * 98304)
                                 : (hfragH + (size_t)(tau - 2) * 98304);
    const _Float16* h0r = rb;
    const _Float16* h1r = rb + 32768;
    const _Float16* h2r = rb + 65536;

    h16x8 a0[8], a1[8], a2[8];
#pragma unroll
    for (int i = 0; i < 8; ++i) {
      int ks = kq * 8 + i;
      size_t off = ((size_t)(tb * 32 + ks) * 64 + lane) * 8;
      a0[i] = *(const h16x8*)(h0r + off);
      a1[i] = *(const h16x8*)(h1r + off);
      a2[i] = *(const h16x8*)(h2r + off);
    }
    float xg0 = 0.f, xg1 = 0.f, xg2 = 0.f, xg3 = 0.f;
    if (tid < 128 && tau < 128) {
      size_t xb = ((size_t)(tau * BB + eb)) * G4 + en;
      xg0 = (float)X0bf[xb];        xg1 = (float)X0bf[xb + 1024];
      xg2 = (float)X0bf[xb + 2048]; xg3 = (float)X0bf[xb + 3072];
    }
    f32x4 acc0 = {}, acc1 = {}, acc2 = {};
#pragma unroll
    for (int i = 0; i < 8; ++i) {
      int ks = kq * 8 + i;
      int jj = lane & 15, q = lane >> 4;
      int kk = (ks * 32 + q * 8) ^ ((jj & 7) << 3);
      const h16x8 bw1i = *(const h16x8*)&ldsW[0 * 16384 + jj * 1024 + kk];
      const h16x8 bw1h = *(const h16x8*)&ldsW[1 * 16384 + jj * 1024 + kk];
      const h16x8 bw2i = *(const h16x8*)&ldsW[2 * 16384 + jj * 1024 + kk];
      const h16x8 bw2h = *(const h16x8*)&ldsW[3 * 16384 + jj * 1024 + kk];
      acc0 = __builtin_amdgcn_mfma_f32_16x16x32_f16(a0[i], w0reg[i], acc0, 0, 0, 0);
      acc1 = __builtin_amdgcn_mfma_f32_16x16x32_f16(a0[i], bw1i, acc1, 0, 0, 0);
      acc1 = __builtin_amdgcn_mfma_f32_16x16x32_f16(a1[i], bw1h, acc1, 0, 0, 0);
      acc2 = __builtin_amdgcn_mfma_f32_16x16x32_f16(a1[i], bw2i, acc2, 0, 0, 0);
      acc2 = __builtin_amdgcn_mfma_f32_16x16x32_f16(a2[i], bw2h, acc2, 0, 0, 0);
    }
    if (kq >= 1) {
      int s = kq - 1;
#pragma unroll
      for (int r = 0; r < 4; ++r) {
        redbuf[((0 * 3 + s) * 2 + tb) * 256 + (row + r) * 16 + col] = acc0[r];
        redbuf[((1 * 3 + s) * 2 + tb) * 256 + (row + r) * 16 + col] = acc1[r];
        redbuf[((2 * 3 + s) * 2 + tb) * 256 + (row + r) * 16 + col] = acc2[r];
      }
    }
    __syncthreads();
    if (kq == 0) {
#pragma unroll
      for (int r = 0; r < 4; ++r) {
        float v0 = acc0[r], v1 = acc1[r], v2 = acc2[r];
#pragma unroll
        for (int s = 0; s < 3; ++s) {
          v0 += redbuf[((0 * 3 + s) * 2 + tb) * 256 + (row + r) * 16 + col];
          v1 += redbuf[((1 * 3 + s) * 2 + tb) * 256 + (row + r) * 16 + col];
          v2 += redbuf[((2 * 3 + s) * 2 + tb) * 256 + (row + r) * 16 + col];
        }
        gbuf[(0 * 32 + tb * 16 + row + r) * 16 + col] = v0;
        gbuf[(1 * 32 + tb * 16 + row + r) * 16 + col] = v1;
        gbuf[(2 * 32 + tb * 16 + row + r) * 16 + col] = v2;
      }
    }
    __syncthreads();
    _Float16 hb2 = (_Float16)0.f;   // layer-2 output, deferred HBM store
    if (tid < 128) {
      if (tau < 128) {
        float gi = gbuf[(0 * 32 + eb) * 16 + eni] + xg0;
        float gf = gbuf[(0 * 32 + eb) * 16 + 4 + eni] + xg1;
        float gg = gbuf[(0 * 32 + eb) * 16 + 8 + eni] + xg2;
        float go = gbuf[(0 * 32 + eb) * 16 + 12 + eni] + xg3;
        c0r = sigmf(gf) * c0r + sigmf(gi) * tanhf(gg);
        hstage[0 * 128 + tid] = (_Float16)(sigmf(go) * tanhf(c0r));
      }
      if (tau >= 1 && tau < 129) {
        float gi = gbuf[(1 * 32 + eb) * 16 + eni] + b1r[0];
        float gf = gbuf[(1 * 32 + eb) * 16 + 4 + eni] + b1r[1];
        float gg = gbuf[(1 * 32 + eb) * 16 + 8 + eni] + b1r[2];
        float go = gbuf[(1 * 32 + eb) * 16 + 12 + eni] + b1r[3];
        c1r = sigmf(gf) * c1r + sigmf(gi) * tanhf(gg);
        hstage[1 * 128 + tid] = (_Float16)(sigmf(go) * tanhf(c1r));
      }
      if (tau >= 2) {
        float gi = gbuf[(2 * 32 + eb) * 16 + eni] + b2r[0];
        float gf = gbuf[(2 * 32 + eb) * 16 + 4 + eni] + b2r[1];
        float gg = gbuf[(2 * 32 + eb) * 16 + 8 + eni] + b2r[2];
        float go = gbuf[(2 * 32 + eb) * 16 + 12 + eni] + b2r[3];
        c2r = sigmf(gf) * c2r + sigmf(gi) * tanhf(gg);
        hb2 = (_Float16)(sigmf(go) * tanhf(c2r));
        hstage[2 * 128 + tid] = hb2;   // exchange copy only; HBM stores deferred
      }
    }
    __syncthreads();
    {
      bool act = (tid < 96) &&
                 ((pk_l == 0) ? (tau < 128)
                  : (pk_l == 1) ? (tau >= 1 && tau < 129)
                                : (tau >= 2 && tau < 129));
      if (act) {
        unsigned long long v = *(const unsigned long long*)&hstage[pk_l * 128 + pk_r * 4];
        __hip_atomic_store(
            (unsigned long long*)(wb + (size_t)pk_l * 32768 + pk_idx), v,
            __ATOMIC_RELAXED, __HIP_MEMORY_SCOPE_AGENT);
      }
      asm volatile("s_waitcnt vmcnt(0)" ::: "memory");   // ONLY the 8B sc1 exchange stores
    }
    __syncthreads();   // all pack stores complete before flag
    if (tid == 0)
      __hip_atomic_store(&arrive[w * 32], (unsigned)(tau + 1), __ATOMIC_RELAXED,
                         __HIP_MEMORY_SCOPE_AGENT);
    // deferred output stores: absorbed by the poll window, off the critical path
    if (tid < 128 && tau >= 2) {
      int t2 = tau - 2;
      h2all[(size_t)(t2 * BB + eb) * HH + en] = hb2;
      concat[(size_t)(t2 * BB + eb) * 2048 + 1024 + en] = hb2;
    }
    if (tau < 129) {
      if (tid < 64) {
        for (;;) {
          bool ok = true;
#pragma unroll
          for (int j = 0; j < 4; ++j) {
            unsigned v = __hip_atomic_load(&arrive[(tid * 4 + j) * 32], __ATOMIC_RELAXED,
                                           __HIP_MEMORY_SCOPE_AGENT);
            ok &= (v >= (unsigned)(tau + 1));
          }
          if (__all(ok)) break;
          __builtin_amdgcn_s_sleep(1);
        }
        asm volatile("" ::: "memory");
      }
      __syncthreads();
    }
  }
}

// ---------------- fused scores+softmax+weighted-context per (t,b) (R11-proven) ----------------
__global__ __launch_bounds__(256) void k_attn(const _Float16* __restrict__ target,
                                              const _Float16* __restrict__ encb,
                                              _Float16* __restrict__ concat) {
  __shared__ float sc[64];
  __shared__ float att[64];
  int m = blockIdx.x, b = m & 31;
  int tid = threadIdx.x, lane = tid & 63, wv = tid >> 6;
  const h16x8* tp = (const h16x8*)(target + (size_t)m * EE + lane * 16);
  h16x8 tg0 = tp[0], tg1 = tp[1];
  for (int si = 0; si < 16; ++si) {
    int s = wv * 16 + si;
    const h16x8* ep = (const h16x8*)(encb + ((size_t)s * BB + b) * EE + lane * 16);
    h16x8 e0 = ep[0], e1 = ep[1];
    float a = 0.f;
#pragma unroll
    for (int j = 0; j < 8; ++j) a += (float)e0[j] * (float)tg0[j];
#pragma unroll
    for (int j = 0; j < 8; ++j) a += (float)e1[j] * (float)tg1[j];
#pragma unroll
    for (int off = 32; off >= 1; off >>= 1) a += __shfl_xor(a, off);
    if (lane == 0) sc[s] = a;
  }
  __syncthreads();
  if (wv == 0) {
    float v = sc[lane], mx = v;
#pragma unroll
    for (int off = 32; off >= 1; off >>= 1) mx = fmaxf(mx, __shfl_xor(mx, off));
    float e = expf(v - mx), sm = e;
#pragma unroll
    for (int off = 32; off >= 1; off >>= 1) sm += __shfl_xor(sm, off);
    att[lane] = e / sm;
  }
  __syncthreads();
  int e4 = tid * 4;
  float a0 = 0, a1 = 0, a2 = 0, a3 = 0;
  for (int s = 0; s < 64; ++s) {
    float wgt = att[s];
    h16x4 ev = *(const h16x4*)(encb + ((size_t)s * BB + b) * EE + e4);
    a0 += wgt * (float)ev[0]; a1 += wgt * (float)ev[1];
    a2 += wgt * (float)ev[2]; a3 += wgt * (float)ev[3];
  }
  h16x4 o; o[0] = (_Float16)a0; o[1] = (_Float16)a1; o[2] = (_Float16)a2; o[3] = (_Float16)a3;
  *(h16x4*)(concat + (size_t)m * 2048 + e4) = o;
}

// ---------------- host ----------------
extern "C" void kernel_launch(void* const* d_in, const int* in_sizes, int n_in,
                              void* d_out, int out_size, void* d_ws, size_t ws_size,
                              hipStream_t stream) {
  const int* tokens = (const int*)d_in[0];
  const float* embW = (const float*)d_in[1];
  const float* Wih = (const float*)d_in[2];
  const float* Whh = (const float*)d_in[3];
  const float* bih = (const float*)d_in[4];
  const float* bhh = (const float*)d_in[5];
  const float* Win = (const float*)d_in[6];
  const float* Wout = (const float*)d_in[7];
  const float* finalb = (const float*)d_in[8];
  const float* enc = (const float*)d_in[9];
  const float* h0 = (const float*)d_in[10];
  const float* c0 = (const float*)d_in[11];
  (void)in_sizes; (void)n_in; (void)out_size;
  if (ws_size < WS_NEEDED) return;

  char* ws = (char*)d_ws;
  unsigned* sync = (unsigned*)(ws + OFF_SYNC);
  _Float16* hfrag0 = (_Float16*)(ws + OFF_HFRAG0);
  _Float16* hfragH = (_Float16*)(ws + OFF_HFRAGH);
  _Float16* emb = (_Float16*)(ws + OFF_EMB);
  _Float16* X0bf = (_Float16*)(ws + OFF_X0);
  _Float16* Wih0b = (_Float16*)(ws + OFF_WIH0);
  _Float16* Wp4 = (_Float16*)(ws + OFF_WP4);
  _Float16* Wp0 = (_Float16*)(ws + OFF_WP0);
  _Float16* embWb = (_Float16*)(ws + OFF_EMBW);
  _Float16* Winb = (_Float16*)(ws + OFF_WIN);
  _Float16* Woutb = (_Float16*)(ws + OFF_WOUT);
  _Float16* encb = (_Float16*)(ws + OFF_ENC);
  _Float16* h2all = (_Float16*)(ws + OFF_H2ALL);
  _Float16* concat = (_Float16*)(ws + OFF_CONCAT);
  _Float16* target = (_Float16*)(ws + OFF_TARGET);
  _Float16* ht = (_Float16*)(ws + OFF_HT);

  const unsigned LDSB = 155648;   // k_recur
  const unsigned LDSG = 98304;    // k_gemm256: 3 slots x (A 16KB + B 16KB)
  static int lds_set = 0;
  if (!lds_set) {
    hipFuncSetAttribute((const void*)k_recur, hipFuncAttributeMaxDynamicSharedMemorySize,
                        (int)LDSB);
    hipFuncSetAttribute((const void*)k_gemm256<0>, hipFuncAttributeMaxDynamicSharedMemorySize,
                        (int)LDSG);
    hipFuncSetAttribute((const void*)k_gemm256<1>, hipFuncAttributeMaxDynamicSharedMemorySize,
                        (int)LDSG);
    lds_set = 1;
  }

  // prep: one merged convert + gather + packs + init
  k_convall<<<4096, 256, 0, stream>>>(embW, embWb, VV * EE / 4,
                                      Wih, Wih0b, G4 * EE / 4,
                                      Win, Winb, EE * EE / 4,
                                      Wout, Woutb, EE * 2048 / 4,
                                      enc, encb, 64 * BB * EE / 4);
  k_gather<<<NROWS, 256, 0, stream>>>(tokens, embWb, emb);
  k_packw4<<<8192, 256, 0, stream>>>(Wih, Whh, Wp4);
  k_packw0<<<4096, 256, 0, stream>>>(Whh, Wp0);
  k_init<<<384, 256, 0, stream>>>(h0, hfrag0, sync);

  // X0 = emb @ Wih0^T + b_ih0 + b_hh0   -> f16 [4096,4096]
  k_gemm256<1><<<16 * 16, 512, LDSG, stream>>>(emb, Wih0b, X0bf, NROWS, G4, EE, bih, bhh);

  // recurrence: REGULAR launch (graph-capturable); co-residency structural
  k_recur<<<256, 512, LDSB, stream>>>(Wp4, Wp0, X0bf, hfrag0, hfragH, h2all, concat,
                                      bih, bhh, c0, sync);

  // attention chain
  k_gemm<1><<<32 * 8, 256, 0, stream>>>(h2all, Winb, target, NROWS, EE, EE, nullptr, nullptr);
  k_attn<<<NROWS, 256, 0, stream>>>(target, encb, concat);
  k_gemm<2><<<32 * 8, 256, 0, stream>>>(concat, Woutb, ht, NROWS, EE, 2048, nullptr, nullptr);

  // logits = ht @ embW^T + final_b  -> f32 d_out
  k_gemm256<0><<<16 * 125, 512, LDSG, stream>>>(ht, embWb, d_out, NROWS, VV, EE, finalb, nullptr);
}

// Round 16
// 1403.089 us; speedup vs baseline: 1.0856x; 1.0036x over previous
//
#include <hip/hip_runtime.h>
#include <cstdint>
#include <cstddef>

#define SEQ   128
#define BB    32
#define EE    1024
#define HH    1024
#define G4    4096
#define VV    32000
#define NROWS 4096   // SEQ*BB

typedef _Float16 h16x8 __attribute__((ext_vector_type(8)));
typedef _Float16 h16x4 __attribute__((ext_vector_type(4)));
typedef float f32x4  __attribute__((ext_vector_type(4)));

#define AS_G(p) ((const __attribute__((address_space(1))) void*)(p))
#define AS_L(p) ((__attribute__((address_space(3))) void*)(p))

__device__ __forceinline__ float sigmf(float x) { return 1.0f / (1.0f + expf(-x)); }

// ---------------- ws layout (bytes) ----------------
// hfrag = monotonic slot ring: slot s holds [3 layers][32768 f16] (196608 B).
// slots 0..2: dedicated region; slots 3..129 overlay EMB+WIH0+TARGET (dead
// during the recurrence).
#define OFF_SYNC    0ull                      // pad[64] + arrive[256] strided 128B
#define OFF_HFRAG0  40960ull                  // 3 slots  * 196608 = 589824
#define OFF_EMB     630784ull                 // [4096][1024] f16   (8388608)
#define OFF_WIH0    9019392ull                // [4096][1024] f16   (8388608)
#define OFF_TARGET  17408000ull               // [4096][1024] f16   (8388608)
#define OFF_HT      25796608ull               // [4096][1024] f16   (8388608)
#define OFF_HFRAGH  630784ull                 // 127 slots * 196608 (overlay)
#define OFF_X0      34185216ull               // [4096][4096] f16   (33554432)
#define OFF_WP4     67739648ull               // 256 wg * 65536 f16 (33554432)
#define OFF_WP0     101294080ull              // 256 wg * 16384 f16 (8388608)
#define OFF_EMBW    109682688ull              // [32000][1024] f16  (65536000)
#define OFF_WIN     175218688ull              // [1024][1024] f16   (2097152)
#define OFF_WOUT    177315840ull              // [1024][2048] f16   (4194304)
#define OFF_ENC     181510144ull              // [64][32][1024] f16 (4194304)
#define OFF_H2ALL   185704448ull              // [4096][1024] f16   (8388608)
#define OFF_CONCAT  194093056ull              // [4096][2048] f16   (16777216)
#define WS_NEEDED   210870272ull

// ---------------- merged f32 -> f16 convert: 5 segments in ONE launch ----------------
__global__ __launch_bounds__(256) void k_convall(const float* __restrict__ s0, _Float16* d0, int n0,
                                                 const float* __restrict__ s1, _Float16* d1, int n1,
                                                 const float* __restrict__ s2, _Float16* d2, int n2,
                                                 const float* __restrict__ s3, _Float16* d3, int n3,
                                                 const float* __restrict__ s4, _Float16* d4, int n4) {
  const int base = blockIdx.x * blockDim.x + threadIdx.x;
  const int st = gridDim.x * blockDim.x;
#pragma unroll 1
  for (int seg = 0; seg < 5; ++seg) {
    const float* s = seg == 0 ? s0 : seg == 1 ? s1 : seg == 2 ? s2 : seg == 3 ? s3 : s4;
    _Float16* d = seg == 0 ? d0 : seg == 1 ? d1 : seg == 2 ? d2 : seg == 3 ? d3 : d4;
    int n = seg == 0 ? n0 : seg == 1 ? n1 : seg == 2 ? n2 : seg == 3 ? n3 : n4;
    for (int i = base; i < n; i += st) {
      float4 v = ((const float4*)s)[i];
      h16x4 o; o[0] = (_Float16)v.x; o[1] = (_Float16)v.y; o[2] = (_Float16)v.z; o[3] = (_Float16)v.w;
      ((h16x4*)d)[i] = o;
    }
  }
}

// ---------------- embedding gather from f16 table ----------------
__global__ __launch_bounds__(256) void k_gather(const int* __restrict__ tok,
                                                const _Float16* __restrict__ embWb,
                                                _Float16* __restrict__ emb) {
  int row = blockIdx.x;                 // row = t*32+b
  int t = tok[row];
  h16x4 v = ((const h16x4*)(embWb + (size_t)t * EE))[threadIdx.x];
  ((h16x4*)(emb + (size_t)row * EE))[threadIdx.x] = v;
}

// ---------------- pack 4 LDS-resident matrices, 8-wide vectorized ----------------
// wg w owns hidden units 4*wp..4*wp+3 with wp=(w&7)*32+(w>>3)  (XCD-local X0 lines)
// XOR swizzle touches k-bits 3..5 only -> 8 consecutive k share one base:
// each thread reads float4 x2 (coalesced) and writes one h16x8 (coalesced).
__global__ __launch_bounds__(256) void k_packw4(const float* __restrict__ Wih,
                                                const float* __restrict__ Whh,
                                                _Float16* __restrict__ out) {
  int i8 = blockIdx.x * blockDim.x + threadIdx.x;
  int st = gridDim.x * blockDim.x;
  const int total8 = 256 * 65536 / 8;
  for (; i8 < total8; i8 += st) {
    int w = i8 >> 13, rem8 = i8 & 8191;
    int wp = (w & 7) * 32 + (w >> 3);
    int mat = rem8 >> 11, jj = (rem8 >> 7) & 15, k0 = (rem8 & 127) * 8;
    int layer = 1 + (mat >> 1), isHH = mat & 1;
    int row = ((jj >> 2) << 10) + (wp << 2) + (jj & 3);
    int ks0 = k0 ^ ((jj & 7) << 3);
    const float* src = (isHH ? Whh : Wih) + (size_t)layer * G4 * 1024 + (size_t)row * 1024 + ks0;
    float4 v0 = *(const float4*)(src);
    float4 v1 = *(const float4*)(src + 4);
    h16x8 o;
    o[0] = (_Float16)v0.x; o[1] = (_Float16)v0.y; o[2] = (_Float16)v0.z; o[3] = (_Float16)v0.w;
    o[4] = (_Float16)v1.x; o[5] = (_Float16)v1.y; o[6] = (_Float16)v1.z; o[7] = (_Float16)v1.w;
    *(h16x8*)(out + (size_t)i8 * 8) = o;
  }
}

// ---------------- pack Whh0 fragment-linear, 8-wide vectorized ----------------
// [w][ks 0..31][lane 0..63][e 0..7]: e runs over 8 consecutive k AND 8
// consecutive out elements -> float4 x2 read, h16x8 write.
__global__ __launch_bounds__(256) void k_packw0(const float* __restrict__ Whh,
                                                _Float16* __restrict__ out) {
  int i8 = blockIdx.x * blockDim.x + threadIdx.x;
  int st = gridDim.x * blockDim.x;
  const int total8 = 256 * 16384 / 8;
  for (; i8 < total8; i8 += st) {
    int w = i8 >> 11, rem8 = i8 & 2047;
    int wp = (w & 7) * 32 + (w >> 3);
    int ks = rem8 >> 6, lane = rem8 & 63;
    int jj = lane & 15, q = lane >> 4;
    int row = ((jj >> 2) << 10) + (wp << 2) + (jj & 3);
    int k0 = ks * 32 + q * 8;
    const float* src = Whh + (size_t)row * 1024 + k0;   // layer 0
    float4 v0 = *(const float4*)(src);
    float4 v1 = *(const float4*)(src + 4);
    h16x8 o;
    o[0] = (_Float16)v0.x; o[1] = (_Float16)v0.y; o[2] = (_Float16)v0.z; o[3] = (_Float16)v0.w;
    o[4] = (_Float16)v1.x; o[5] = (_Float16)v1.y; o[6] = (_Float16)v1.z; o[7] = (_Float16)v1.w;
    *(h16x8*)(out + (size_t)i8 * 8) = o;
  }
}

// ---------------- init: sync flags + initial h into slots 0..2 ----------------
__global__ __launch_bounds__(256) void k_init(const float* __restrict__ h0,
                                              _Float16* __restrict__ hfrag0,
                                              unsigned* __restrict__ sync) {
  int i = blockIdx.x * blockDim.x + threadIdx.x;
  if (i < 64 + 8192) sync[i] = 0u;   // pad + arrive (strided)
  if (i >= 3 * BB * HH) return;
  int l = i >> 15, rem = i & 32767;
  int b = rem >> 10, n = rem & 1023;
  int tbb = b >> 4, ks = n >> 5, q = (n >> 3) & 3, e = n & 7;
  int lane2 = (b & 15) | (q << 4);
  hfrag0[(size_t)l * 131072 + ((size_t)(tbb * 32 + ks) * 64 + lane2) * 8 + e] =
      (_Float16)h0[i];
}

// ---------------- generic 128x128 BT GEMM (A[M,K] f16, B[N,K] f16) ----------------
// EPI: 1 = f16 ; 2 = f16(tanh)   (big GEMMs use k_gemm256)
template <int EPI>
__global__ __launch_bounds__(256) void k_gemm(const _Float16* __restrict__ A,
                                              const _Float16* __restrict__ B,
                                              void* __restrict__ C, int M, int N, int K,
                                              const float* __restrict__ bias1,
                                              const float* __restrict__ bias2) {
  __shared__ _Float16 As[2][128 * 32];
  __shared__ _Float16 Bs[2][128 * 32];
  const int ntn = N / 128;
  const int nwg = gridDim.x;
  const int bid = (blockIdx.x & 7) * (nwg >> 3) + (blockIdx.x >> 3);
  const int tm = bid / ntn, tn = bid % ntn;
  const int tid = threadIdx.x, lane = tid & 63;
  const int wv = tid >> 6, wr = wv >> 1, wc = wv & 1;
  f32x4 acc[4][4] = {};

  auto stage = [&](int buf, int k0) {
#pragma unroll
    for (int i = 0; i < 2; ++i) {
      int eo = (i * 256 + tid) * 8;
      int r = eo >> 5, c = eo & 31;
      __builtin_amdgcn_global_load_lds(AS_G(A + (size_t)(tm * 128 + r) * K + k0 + c),
                                       AS_L(&As[buf][eo]), 16, 0, 0);
      __builtin_amdgcn_global_load_lds(AS_G(B + (size_t)(tn * 128 + r) * K + k0 + c),
                                       AS_L(&Bs[buf][eo]), 16, 0, 0);
    }
  };
  stage(0, 0);
  __syncthreads();
  const int nk = K / 32;
  for (int kt = 0; kt < nk; ++kt) {
    if (kt + 1 < nk) stage((kt + 1) & 1, (kt + 1) * 32);
    const int buf = kt & 1;
    h16x8 af[4], bfr[4];
#pragma unroll
    for (int mi = 0; mi < 4; ++mi)
      af[mi] = *(const h16x8*)&As[buf][(wr * 64 + mi * 16 + (lane & 15)) * 32 + (lane >> 4) * 8];
#pragma unroll
    for (int ni = 0; ni < 4; ++ni)
      bfr[ni] = *(const h16x8*)&Bs[buf][(wc * 64 + ni * 16 + (lane & 15)) * 32 + (lane >> 4) * 8];
#pragma unroll
    for (int mi = 0; mi < 4; ++mi)
#pragma unroll
      for (int ni = 0; ni < 4; ++ni)
        acc[mi][ni] = __builtin_amdgcn_mfma_f32_16x16x32_f16(af[mi], bfr[ni], acc[mi][ni], 0, 0, 0);
    __syncthreads();
  }
  const int rbase = tm * 128 + wr * 64;
  const int cbase = tn * 128 + wc * 64;
#pragma unroll
  for (int mi = 0; mi < 4; ++mi) {
#pragma unroll
    for (int ni = 0; ni < 4; ++ni) {
#pragma unroll
      for (int r = 0; r < 4; ++r) {
        int mm = rbase + mi * 16 + (lane >> 4) * 4 + r;
        int nn = cbase + ni * 16 + (lane & 15);
        float v = acc[mi][ni][r];
        if (EPI == 1) {
          ((_Float16*)C)[(size_t)mm * N + nn] = (_Float16)v;
        } else {
          ((_Float16*)C)[(size_t)mm * N + nn] = (_Float16)tanhf(v);
        }
      }
    }
  }
}

// ---------------- 256x256 BT GEMM, 3-slot LDS ring + counted vmcnt (T4) ----------------
// R11-proven: 512 thr, 8 waves, depth-2 prefetch, vmcnt(4), tm-MAJOR mapping.
// EPI: 0 = f32 + bias1 ; 1 = f16 + bias1 + bias2
template <int EPI>
__global__ __launch_bounds__(512, 2) void k_gemm256(const _Float16* __restrict__ A,
                                                    const _Float16* __restrict__ B,
                                                    void* __restrict__ C, int M, int N, int K,
                                                    const float* __restrict__ bias1,
                                                    const float* __restrict__ bias2) {
  extern __shared__ char glds[];
  _Float16* Asl = (_Float16*)glds;                     // [3][256*32]
  _Float16* Bsl = (_Float16*)(glds + 3 * 8192 * 2);    // [3][256*32]
  const int ntn = N / 256;
  const int nwg = gridDim.x;
  const int bid = (blockIdx.x & 7) * (nwg >> 3) + (blockIdx.x >> 3);
  const int tm = bid / ntn, tn = bid % ntn;            // tm-major (R11)
  const int tid = threadIdx.x, lane = tid & 63;
  const int wid = tid >> 6, wm = wid >> 2, wn = wid & 3;
  const int fr = lane & 15, fc = lane >> 4;
  const int srow0 = tid >> 2, sg = tid & 3;    // staging: row within 128-half, granule

  f32x4 acc[8][4] = {};
  const int nt = K / 32;

  auto stage = [&](int t) {
    const int slot = t % 3;
    const size_t kof = (size_t)t * 32 + sg * 8;
#pragma unroll
    for (int r = 0; r < 2; ++r) {
      int row = r * 128 + srow0;
      __builtin_amdgcn_global_load_lds(AS_G(A + (size_t)(tm * 256 + row) * K + kof),
                                       AS_L(&Asl[slot * 8192 + row * 32 + sg * 8]), 16, 0, 0);
    }
#pragma unroll
    for (int r = 0; r < 2; ++r) {
      int row = r * 128 + srow0;
      __builtin_amdgcn_global_load_lds(AS_G(B + (size_t)(tn * 256 + row) * K + kof),
                                       AS_L(&Bsl[slot * 8192 + row * 32 + sg * 8]), 16, 0, 0);
    }
  };

  stage(0);
  stage(1);
  asm volatile("s_waitcnt vmcnt(4)" ::: "memory");   // tile 0 landed (mine)
  asm volatile("s_barrier" ::: "memory");            // tile 0 landed (all waves)

  for (int t = 0; t < nt; ++t) {
    if (t + 2 < nt) {
      stage(t + 2);
      asm volatile("s_waitcnt vmcnt(4)" ::: "memory");   // tile t+1 landed; t+2 in flight
    } else {
      asm volatile("s_waitcnt vmcnt(0)" ::: "memory");   // tail drain
    }
    asm volatile("s_barrier" ::: "memory");              // globalize tile t+1 / protect ring
    const int slot = t % 3;
    const _Float16* as = &Asl[slot * 8192];
    const _Float16* bs = &Bsl[slot * 8192];
    h16x8 af[8], bf[4];
#pragma unroll
    for (int mi = 0; mi < 8; ++mi)
      af[mi] = *(const h16x8*)&as[(wm * 128 + mi * 16 + fr) * 32 + fc * 8];
#pragma unroll
    for (int ni = 0; ni < 4; ++ni)
      bf[ni] = *(const h16x8*)&bs[(wn * 64 + ni * 16 + fr) * 32 + fc * 8];
    __builtin_amdgcn_s_setprio(1);
#pragma unroll
    for (int mi = 0; mi < 8; ++mi)
#pragma unroll
      for (int ni = 0; ni < 4; ++ni)
        acc[mi][ni] = __builtin_amdgcn_mfma_f32_16x16x32_f16(af[mi], bf[ni], acc[mi][ni], 0, 0, 0);
    __builtin_amdgcn_s_setprio(0);
    asm volatile("s_barrier" ::: "memory");   // my reads of slot done before others restage it
  }

  const int rbase = tm * 256 + wm * 128;
  const int cbase = tn * 256 + wn * 64;
#pragma unroll
  for (int mi = 0; mi < 8; ++mi) {
#pragma unroll
    for (int ni = 0; ni < 4; ++ni) {
#pragma unroll
      for (int r = 0; r < 4; ++r) {
        int mm = rbase + mi * 16 + fc * 4 + r;
        int nn = cbase + ni * 16 + fr;
        float v = acc[mi][ni][r];
        if (EPI == 0) {
          ((float*)C)[(size_t)mm * N + nn] = v + bias1[nn];
        } else {
          ((_Float16*)C)[(size_t)mm * N + nn] = (_Float16)(v + bias1[nn] + bias2[nn]);
        }
      }
    }
  }
}

// ---------------- persistent pipelined LSTM recurrence (R15-proven, unchanged) ----------------
__global__ __launch_bounds__(512) void k_recur(const _Float16* __restrict__ Wp4,
                                               const _Float16* __restrict__ Wp0,
                                               const _Float16* __restrict__ X0bf,
                                               _Float16* __restrict__ hfrag0,
                                               _Float16* __restrict__ hfragH,
                                               _Float16* __restrict__ h2all,
                                               _Float16* __restrict__ concat,
                                               const float* __restrict__ bih,
                                               const float* __restrict__ bhh,
                                               const float* __restrict__ c0p,
                                               unsigned* __restrict__ sync) {
  extern __shared__ char lds[];
  _Float16* ldsW = (_Float16*)lds;                 // 65536 f16
  float* redbuf = (float*)(lds + 131072);          // [3][3][2][256]
  _Float16* hstage = (_Float16*)(lds + 131072);    // [3][128] (reused after redbuf)
  float* gbuf = (float*)(lds + 149504);            // [3][32][16]
  unsigned* arrive = sync + 64;                    // strided: arrive[w*32]

  const int w = blockIdx.x;
  const int wp = (w & 7) * 32 + (w >> 3);          // XCD-local unit-block remap
  const int tid = threadIdx.x, lane = tid & 63, wv = tid >> 6;
  const int tb = wv & 1, kq = wv >> 1;
  const int row = (lane >> 4) * 4, col = lane & 15;

  for (int i = 0; i < 16; ++i) {
    int eo = (i * 512 + tid) * 8;
    *(h16x8*)&ldsW[eo] = *(const h16x8*)(Wp4 + (size_t)w * 65536 + eo);
  }
  h16x8 w0reg[8];
#pragma unroll
  for (int i = 0; i < 8; ++i)
    w0reg[i] = *(const h16x8*)(Wp0 + (size_t)w * 16384 + ((size_t)(kq * 8 + i) * 64 + lane) * 8);

  const int eb = tid >> 2, eni = tid & 3, en = wp * 4 + eni;
  float c0r = 0.f, c1r = 0.f, c2r = 0.f;
  float b1r[4] = {0, 0, 0, 0}, b2r[4] = {0, 0, 0, 0};
  if (tid < 128) {
    c0r = c0p[0 * BB * HH + eb * HH + en];
    c1r = c0p[1 * BB * HH + eb * HH + en];
    c2r = c0p[2 * BB * HH + eb * HH + en];
#pragma unroll
    for (int g = 0; g < 4; ++g) {
      b1r[g] = bih[1 * G4 + g * 1024 + en] + bhh[1 * G4 + g * 1024 + en];
      b2r[g] = bih[2 * G4 + g * 1024 + en] + bhh[2 * G4 + g * 1024 + en];
    }
  }
  const int pk_l = tid >> 5, pk_r = tid & 31;
  const size_t pk_idx = ((size_t)(((pk_r >> 4) * 32 + (wp >> 3)) * 64 + (pk_r & 15) +
                                  (((wp >> 1) & 3) << 4))) * 8 + 4 * (wp & 1);
  __syncthreads();

  for (int tau = 0; tau < 130; ++tau) {
    const _Float16* rb = (tau < 3) ? (hfrag0 + (size_t)tau * 98304)
                                   : (hfragH + (size_t)(tau - 3) * 98304);
    _Float16* wb = (tau + 1 < 3) ? (hfrag0 + (size_t)(tau + 1) * 98304)
                                 : (hfragH + (size_t)(tau - 2) * 98304);
    const _Float16* h0r = rb;
    const _Float16* h1r = rb + 32768;
    const _Float16* h2r = rb + 65536;

    h16x8 a0[8], a1[8], a2[8];
#pragma unroll
    for (int i = 0; i < 8; ++i) {
      int ks = kq * 8 + i;
      size_t off = ((size_t)(tb * 32 + ks) * 64 + lane) * 8;
      a0[i] = *(const h16x8*)(h0r + off);
      a1[i] = *(const h16x8*)(h1r + off);
      a2[i] = *(const h16x8*)(h2r + off);
    }
    float xg0 = 0.f, xg1 = 0.f, xg2 = 0.f, xg3 = 0.f;
    if (tid < 128 && tau < 128) {
      size_t xb = ((size_t)(tau * BB + eb)) * G4 + en;
      xg0 = (float)X0bf[xb];        xg1 = (float)X0bf[xb + 1024];
      xg2 = (float)X0bf[xb + 2048]; xg3 = (float)X0bf[xb + 3072];
    }
    f32x4 acc0 = {}, acc1 = {}, acc2 = {};
#pragma unroll
    for (int i = 0; i < 8; ++i) {
      int ks = kq * 8 + i;
      int jj = lane & 15, q = lane >> 4;
      int kk = (ks * 32 + q * 8) ^ ((jj & 7) << 3);
      const h16x8 bw1i = *(const h16x8*)&ldsW[0 * 16384 + jj * 1024 + kk];
      const h16x8 bw1h = *(const h16x8*)&ldsW[1 * 16384 + jj * 1024 + kk];
      const h16x8 bw2i = *(const h16x8*)&ldsW[2 * 16384 + jj * 1024 + kk];
      const h16x8 bw2h = *(const h16x8*)&ldsW[3 * 16384 + jj * 1024 + kk];
      acc0 = __builtin_amdgcn_mfma_f32_16x16x32_f16(a0[i], w0reg[i], acc0, 0, 0, 0);
      acc1 = __builtin_amdgcn_mfma_f32_16x16x32_f16(a0[i], bw1i, acc1, 0, 0, 0);
      acc1 = __builtin_amdgcn_mfma_f32_16x16x32_f16(a1[i], bw1h, acc1, 0, 0, 0);
      acc2 = __builtin_amdgcn_mfma_f32_16x16x32_f16(a1[i], bw2i, acc2, 0, 0, 0);
      acc2 = __builtin_amdgcn_mfma_f32_16x16x32_f16(a2[i], bw2h, acc2, 0, 0, 0);
    }
    if (kq >= 1) {
      int s = kq - 1;
#pragma unroll
      for (int r = 0; r < 4; ++r) {
        redbuf[((0 * 3 + s) * 2 + tb) * 256 + (row + r) * 16 + col] = acc0[r];
        redbuf[((1 * 3 + s) * 2 + tb) * 256 + (row + r) * 16 + col] = acc1[r];
        redbuf[((2 * 3 + s) * 2 + tb) * 256 + (row + r) * 16 + col] = acc2[r];
      }
    }
    __syncthreads();
    if (kq == 0) {
#pragma unroll
      for (int r = 0; r < 4; ++r) {
        float v0 = acc0[r], v1 = acc1[r], v2 = acc2[r];
#pragma unroll
        for (int s = 0; s < 3; ++s) {
          v0 += redbuf[((0 * 3 + s) * 2 + tb) * 256 + (row + r) * 16 + col];
          v1 += redbuf[((1 * 3 + s) * 2 + tb) * 256 + (row + r) * 16 + col];
          v2 += redbuf[((2 * 3 + s) * 2 + tb) * 256 + (row + r) * 16 + col];
        }
        gbuf[(0 * 32 + tb * 16 + row + r) * 16 + col] = v0;
        gbuf[(1 * 32 + tb * 16 + row + r) * 16 + col] = v1;
        gbuf[(2 * 32 + tb * 16 + row + r) * 16 + col] = v2;
      }
    }
    __syncthreads();
    _Float16 hb2 = (_Float16)0.f;   // layer-2 output, deferred HBM store
    if (tid < 128) {
      if (tau < 128) {
        float gi = gbuf[(0 * 32 + eb) * 16 + eni] + xg0;
        float gf = gbuf[(0 * 32 + eb) * 16 + 4 + eni] + xg1;
        float gg = gbuf[(0 * 32 + eb) * 16 + 8 + eni] + xg2;
        float go = gbuf[(0 * 32 + eb) * 16 + 12 + eni] + xg3;
        c0r = sigmf(gf) * c0r + sigmf(gi) * tanhf(gg);
        hstage[0 * 128 + tid] = (_Float16)(sigmf(go) * tanhf(c0r));
      }
      if (tau >= 1 && tau < 129) {
        float gi = gbuf[(1 * 32 + eb) * 16 + eni] + b1r[0];
        float gf = gbuf[(1 * 32 + eb) * 16 + 4 + eni] + b1r[1];
        float gg = gbuf[(1 * 32 + eb) * 16 + 8 + eni] + b1r[2];
        float go = gbuf[(1 * 32 + eb) * 16 + 12 + eni] + b1r[3];
        c1r = sigmf(gf) * c1r + sigmf(gi) * tanhf(gg);
        hstage[1 * 128 + tid] = (_Float16)(sigmf(go) * tanhf(c1r));
      }
      if (tau >= 2) {
        float gi = gbuf[(2 * 32 + eb) * 16 + eni] + b2r[0];
        float gf = gbuf[(2 * 32 + eb) * 16 + 4 + eni] + b2r[1];
        float gg = gbuf[(2 * 32 + eb) * 16 + 8 + eni] + b2r[2];
        float go = gbuf[(2 * 32 + eb) * 16 + 12 + eni] + b2r[3];
        c2r = sigmf(gf) * c2r + sigmf(gi) * tanhf(gg);
        hb2 = (_Float16)(sigmf(go) * tanhf(c2r));
        hstage[2 * 128 + tid] = hb2;   // exchange copy only; HBM stores deferred
      }
    }
    __syncthreads();
    {
      bool act = (tid < 96) &&
                 ((pk_l == 0) ? (tau < 128)
                  : (pk_l == 1) ? (tau >= 1 && tau < 129)
                                : (tau >= 2 && tau < 129));
      if (act) {
        unsigned long long v = *(const unsigned long long*)&hstage[pk_l * 128 + pk_r * 4];
        __hip_atomic_store(
            (unsigned long long*)(wb + (size_t)pk_l * 32768 + pk_idx), v,
            __ATOMIC_RELAXED, __HIP_MEMORY_SCOPE_AGENT);
      }
      asm volatile("s_waitcnt vmcnt(0)" ::: "memory");   // ONLY the 8B sc1 exchange stores
    }
    __syncthreads();   // all pack stores complete before flag
    if (tid == 0)
      __hip_atomic_store(&arrive[w * 32], (unsigned)(tau + 1), __ATOMIC_RELAXED,
                         __HIP_MEMORY_SCOPE_AGENT);
    // deferred output stores: absorbed by the poll window, off the critical path
    if (tid < 128 && tau >= 2) {
      int t2 = tau - 2;
      h2all[(size_t)(t2 * BB + eb) * HH + en] = hb2;
      concat[(size_t)(t2 * BB + eb) * 2048 + 1024 + en] = hb2;
    }
    if (tau < 129) {
      if (tid < 64) {
        for (;;) {
          bool ok = true;
#pragma unroll
          for (int j = 0; j < 4; ++j) {
            unsigned v = __hip_atomic_load(&arrive[(tid * 4 + j) * 32], __ATOMIC_RELAXED,
                                           __HIP_MEMORY_SCOPE_AGENT);
            ok &= (v >= (unsigned)(tau + 1));
          }
          if (__all(ok)) break;
          __builtin_amdgcn_s_sleep(1);
        }
        asm volatile("" ::: "memory");
      }
      __syncthreads();
    }
  }
}

// ---------------- fused scores+softmax+weighted-context per (t,b) (R11-proven) ----------------
__global__ __launch_bounds__(256) void k_attn(const _Float16* __restrict__ target,
                                              const _Float16* __restrict__ encb,
                                              _Float16* __restrict__ concat) {
  __shared__ float sc[64];
  __shared__ float att[64];
  int m = blockIdx.x, b = m & 31;
  int tid = threadIdx.x, lane = tid & 63, wv = tid >> 6;
  const h16x8* tp = (const h16x8*)(target + (size_t)m * EE + lane * 16);
  h16x8 tg0 = tp[0], tg1 = tp[1];
  for (int si = 0; si < 16; ++si) {
    int s = wv * 16 + si;
    const h16x8* ep = (const h16x8*)(encb + ((size_t)s * BB + b) * EE + lane * 16);
    h16x8 e0 = ep[0], e1 = ep[1];
    float a = 0.f;
#pragma unroll
    for (int j = 0; j < 8; ++j) a += (float)e0[j] * (float)tg0[j];
#pragma unroll
    for (int j = 0; j < 8; ++j) a += (float)e1[j] * (float)tg1[j];
#pragma unroll
    for (int off = 32; off >= 1; off >>= 1) a += __shfl_xor(a, off);
    if (lane == 0) sc[s] = a;
  }
  __syncthreads();
  if (wv == 0) {
    float v = sc[lane], mx = v;
#pragma unroll
    for (int off = 32; off >= 1; off >>= 1) mx = fmaxf(mx, __shfl_xor(mx, off));
    float e = expf(v - mx), sm = e;
#pragma unroll
    for (int off = 32; off >= 1; off >>= 1) sm += __shfl_xor(sm, off);
    att[lane] = e / sm;
  }
  __syncthreads();
  int e4 = tid * 4;
  float a0 = 0, a1 = 0, a2 = 0, a3 = 0;
  for (int s = 0; s < 64; ++s) {
    float wgt = att[s];
    h16x4 ev = *(const h16x4*)(encb + ((size_t)s * BB + b) * EE + e4);
    a0 += wgt * (float)ev[0]; a1 += wgt * (float)ev[1];
    a2 += wgt * (float)ev[2]; a3 += wgt * (float)ev[3];
  }
  h16x4 o; o[0] = (_Float16)a0; o[1] = (_Float16)a1; o[2] = (_Float16)a2; o[3] = (_Float16)a3;
  *(h16x4*)(concat + (size_t)m * 2048 + e4) = o;
}

// ---------------- host ----------------
extern "C" void kernel_launch(void* const* d_in, const int* in_sizes, int n_in,
                              void* d_out, int out_size, void* d_ws, size_t ws_size,
                              hipStream_t stream) {
  const int* tokens = (const int*)d_in[0];
  const float* embW = (const float*)d_in[1];
  const float* Wih = (const float*)d_in[2];
  const float* Whh = (const float*)d_in[3];
  const float* bih = (const float*)d_in[4];
  const float* bhh = (const float*)d_in[5];
  const float* Win = (const float*)d_in[6];
  const float* Wout = (const float*)d_in[7];
  const float* finalb = (const float*)d_in[8];
  const float* enc = (const float*)d_in[9];
  const float* h0 = (const float*)d_in[10];
  const float* c0 = (const float*)d_in[11];
  (void)in_sizes; (void)n_in; (void)out_size;
  if (ws_size < WS_NEEDED) return;

  char* ws = (char*)d_ws;
  unsigned* sync = (unsigned*)(ws + OFF_SYNC);
  _Float16* hfrag0 = (_Float16*)(ws + OFF_HFRAG0);
  _Float16* hfragH = (_Float16*)(ws + OFF_HFRAGH);
  _Float16* emb = (_Float16*)(ws + OFF_EMB);
  _Float16* X0bf = (_Float16*)(ws + OFF_X0);
  _Float16* Wih0b = (_Float16*)(ws + OFF_WIH0);
  _Float16* Wp4 = (_Float16*)(ws + OFF_WP4);
  _Float16* Wp0 = (_Float16*)(ws + OFF_WP0);
  _Float16* embWb = (_Float16*)(ws + OFF_EMBW);
  _Float16* Winb = (_Float16*)(ws + OFF_WIN);
  _Float16* Woutb = (_Float16*)(ws + OFF_WOUT);
  _Float16* encb = (_Float16*)(ws + OFF_ENC);
  _Float16* h2all = (_Float16*)(ws + OFF_H2ALL);
  _Float16* concat = (_Float16*)(ws + OFF_CONCAT);
  _Float16* target = (_Float16*)(ws + OFF_TARGET);
  _Float16* ht = (_Float16*)(ws + OFF_HT);

  const unsigned LDSB = 155648;   // k_recur
  const unsigned LDSG = 98304;    // k_gemm256: 3 slots x (A 16KB + B 16KB)
  static int lds_set = 0;
  if (!lds_set) {
    hipFuncSetAttribute((const void*)k_recur, hipFuncAttributeMaxDynamicSharedMemorySize,
                        (int)LDSB);
    hipFuncSetAttribute((const void*)k_gemm256<0>, hipFuncAttributeMaxDynamicSharedMemorySize,
                        (int)LDSG);
    hipFuncSetAttribute((const void*)k_gemm256<1>, hipFuncAttributeMaxDynamicSharedMemorySize,
                        (int)LDSG);
    lds_set = 1;
  }

  // prep: one merged convert + gather + packs (8-wide vectorized) + init
  k_convall<<<4096, 256, 0, stream>>>(embW, embWb, VV * EE / 4,
                                      Wih, Wih0b, G4 * EE / 4,
                                      Win, Winb, EE * EE / 4,
                                      Wout, Woutb, EE * 2048 / 4,
                                      enc, encb, 64 * BB * EE / 4);
  k_gather<<<NROWS, 256, 0, stream>>>(tokens, embWb, emb);
  k_packw4<<<2048, 256, 0, stream>>>(Wih, Whh, Wp4);
  k_packw0<<<512, 256, 0, stream>>>(Whh, Wp0);
  k_init<<<384, 256, 0, stream>>>(h0, hfrag0, sync);

  // X0 = emb @ Wih0^T + b_ih0 + b_hh0   -> f16 [4096,4096]
  k_gemm256<1><<<16 * 16, 512, LDSG, stream>>>(emb, Wih0b, X0bf, NROWS, G4, EE, bih, bhh);

  // recurrence: REGULAR launch (graph-capturable); co-residency structural
  k_recur<<<256, 512, LDSB, stream>>>(Wp4, Wp0, X0bf, hfrag0, hfragH, h2all, concat,
                                      bih, bhh, c0, sync);

  // attention chain
  k_gemm<1><<<32 * 8, 256, 0, stream>>>(h2all, Winb, target, NROWS, EE, EE, nullptr, nullptr);
  k_attn<<<NROWS, 256, 0, stream>>>(target, encb, concat);
  k_gemm<2><<<32 * 8, 256, 0, stream>>>(concat, Woutb, ht, NROWS, EE, 2048, nullptr, nullptr);

  // logits = ht @ embW^T + final_b  -> f32 d_out
  k_gemm256<0><<<16 * 125, 512, LDSG, stream>>>(ht, embWb, d_out, NROWS, VV, EE, finalb, nullptr);
}